// Round 4
// baseline (679.658 us; speedup 1.0000x reference)
//
#include <hip/hip_runtime.h>
#include <cstdint>
#include <cstddef>

typedef unsigned short u16;
typedef __attribute__((ext_vector_type(8))) short short8;
typedef __attribute__((ext_vector_type(4))) float f32x4;

// ---------- constants (match reference) ----------
#define HC_ 128
#define CAP 32            // in-degree bucket capacity (Poisson(4) tail ~1e-18)
// dot-table row offsets (rows of 4 floats)
#define OFF_U0   0
#define OFF_I0   202
#define OFF_T0   404
#define OFF_UD0  606
#define OFF_ID0  1107
#define OFF_U2   1608
#define OFF_I2   2410
#define OFF_T2   3212
#define OFF_UD2  4014
#define OFF_ID2  4515
#define DOT_ROWS 5016

__device__ __forceinline__ float b2f(u16 u) {
  union { unsigned int i; float f; } v; v.i = ((unsigned int)u) << 16; return v.f;
}
__device__ __forceinline__ u16 f2b(float f) {
  union { float f; unsigned int i; } v; v.f = f;
  unsigned int r = v.i + 0x7fffu + ((v.i >> 16) & 1u);
  return (u16)(r >> 16);
}

// ================= fused prolog: zero cur/kdot, gather x, dots, wq, cvt rnn, Wt ========
__global__ __launch_bounds__(256) void prolog_k(
    const int* __restrict__ nidx, const float* __restrict__ emb, u16* __restrict__ x,
    const float* u0, const float* i0, const float* t0, const float* ud0, const float* id0,
    const float* u2, const float* i2, const float* t2, const float* ud2, const float* id2,
    const float* __restrict__ asrc0, const float* __restrict__ asrc1,
    float* __restrict__ dots,
    const float* __restrict__ wr0, const float* __restrict__ adst0,
    const float* __restrict__ wr1, const float* __restrict__ adst1,
    float* __restrict__ wq,
    const float* __restrict__ rnn_w, u16* __restrict__ rnn_wb,
    const float* __restrict__ th, u16* __restrict__ Wt,
    int* __restrict__ cur, float* __restrict__ kdot0, float* __restrict__ kdot1, int Nn)
{
  int b = blockIdx.x, t = threadIdx.x;
  const int nbCur  = (Nn + 255) >> 8;
  const int nbKd   = (Nn * 4 + 255) >> 8;
  const int nbGx   = (Nn * 16 + 255) >> 8;
  const int nbDots = (DOT_ROWS * 4 + 255) >> 8;

  if (b < nbCur) { int i = b * 256 + t; if (i < Nn) cur[i] = 0; return; }
  b -= nbCur;
  if (b < nbKd) {
    int i = b * 256 + t;
    if (i < Nn * 4) { kdot0[i] = 0.f; kdot1[i] = 0.f; }
    return;
  }
  b -= nbKd;
  if (b < nbGx) {  // x = bf16(id_emb[node_idx])
    int i = b * 256 + t;
    int n = i >> 4, c = (i & 15) << 3;
    if (n < Nn) {
      int id = nidx[n];
      const float* s = emb + (size_t)id * HC_ + c;
      u16 tmp[8];
#pragma unroll
      for (int j = 0; j < 8; ++j) tmp[j] = f2b(s[j]);
      *(short8*)(x + (size_t)n * HC_ + c) = *(short8*)tmp;
    }
    return;
  }
  b -= nbGx;
  if (b < nbDots) {  // att-bias dot tables
    int i = b * 256 + t;
    if (i < DOT_ROWS * 4) {
      int r = i >> 2, h = i & 3;
      const float* tab; int lr; const float* as;
      if      (r < OFF_I0)  { tab = u0;  lr = r;            as = asrc0; }
      else if (r < OFF_T0)  { tab = i0;  lr = r - OFF_I0;   as = asrc0; }
      else if (r < OFF_UD0) { tab = t0;  lr = r - OFF_T0;   as = asrc0; }
      else if (r < OFF_ID0) { tab = ud0; lr = r - OFF_UD0;  as = asrc0; }
      else if (r < OFF_U2)  { tab = id0; lr = r - OFF_ID0;  as = asrc0; }
      else if (r < OFF_I2)  { tab = u2;  lr = r - OFF_U2;   as = asrc1; }
      else if (r < OFF_T2)  { tab = i2;  lr = r - OFF_I2;   as = asrc1; }
      else if (r < OFF_UD2) { tab = t2;  lr = r - OFF_T2;   as = asrc1; }
      else if (r < OFF_ID2) { tab = ud2; lr = r - OFF_UD2;  as = asrc1; }
      else                  { tab = id2; lr = r - OFF_ID2;  as = asrc1; }
      float s = 0.f;
#pragma unroll
      for (int c = 0; c < 32; ++c)
        s += tab[(size_t)lr * HC_ + h * 32 + c] * as[h * 32 + c];
      dots[i] = s;
    }
    return;
  }
  b -= nbDots;
  if (b < 4) {  // wq[layer][k][h]
    int i = b * 256 + t;
    int layer = i >> 9, k = (i >> 2) & 127, h = i & 3;
    const float* wr = layer ? wr1 : wr0;
    const float* ad = layer ? adst1 : adst0;
    float s = 0.f;
#pragma unroll
    for (int c = 0; c < 32; ++c)
      s += wr[(size_t)k * HC_ + h * 32 + c] * ad[h * 32 + c];
    wq[i] = s;
    return;
  }
  b -= 4;
  if (b < 128) {  // rnn_w -> bf16
    int i = b * 256 + t;
    rnn_wb[i] = f2b(rnn_w[i]);
    return;
  }
  b -= 128;
  {  // Wt = bf16(trans_head @ rnn_w[128:,:]), 16384 outputs
    int i = b * 256 + t;
    if (i < 16384) {
      int r = i >> 7, c = i & 127;
      float s = 0.f;
#pragma unroll 8
      for (int k = 0; k < 128; ++k)
        s += th[r * 128 + k] * rnn_w[(size_t)(128 + k) * 128 + c];
      Wt[i] = f2b(s);
    }
  }
}

// ================= bucket fill (SoA): meta {src, ty|to<<3|di<<13} + edot f32x4 =========
__global__ void fill_k(const int* __restrict__ src, const int* __restrict__ dst,
                       const int* __restrict__ ety,
                       const int* __restrict__ toff0, const int* __restrict__ toff1,
                       const int* __restrict__ dist0, const int* __restrict__ dist1,
                       const float* __restrict__ dots,
                       int* __restrict__ cur,
                       int2* __restrict__ m0a, f32x4* __restrict__ e0a,
                       int2* __restrict__ m1a, f32x4* __restrict__ e1a, int E)
{
  int e = blockIdx.x * blockDim.x + threadIdx.x;
  if (e >= E) return;
  int d = dst[e];
  int slot = atomicAdd(&cur[d], 1);
  if (slot >= CAP) return;   // statistically unreachable
  int s = src[e], ty = ety[e];
  int to0 = toff0[e], to1 = toff1[e], di0 = dist0[e], di1 = dist1[e];
  bool inv = (ty == 0 || ty == 2 || ty == 3);
  int ar0 = (ty == 0) ? (OFF_U0 + to0) : (ty < 2) ? (OFF_I0 + to0) : (OFF_T0 + to0);
  int ar1 = (ty == 0) ? (OFF_U2 + to1) : (ty < 2) ? (OFF_I2 + to1) : (OFF_T2 + to1);
  f32x4 e0 = *(const f32x4*)(dots + (size_t)ar0 * 4);
  f32x4 e1 = *(const f32x4*)(dots + (size_t)ar1 * 4);
  if (inv) {
    int dr0 = ((ty == 0) ? OFF_UD0 : OFF_ID0) + di0;
    int dr1 = ((ty == 0) ? OFF_UD2 : OFF_ID2) + di1;
    e0 += *(const f32x4*)(dots + (size_t)dr0 * 4);
    e1 += *(const f32x4*)(dots + (size_t)dr1 * 4);
  }
  size_t ix = (size_t)d * CAP + slot;
  m0a[ix] = make_int2(s, ty | (to0 << 3) | (di0 << 13));
  m1a[ix] = make_int2(s, ty | (to1 << 3) | (di1 << 13));
  e0a[ix] = e0;
  e1a[ix] = e1;
}

// ---------- generic MFMA GEMM: C[M,N] = epi(A[M,K] @ W[K,N]) ----------
// KQ: fused kdot/qdot epilogue (requires N==128, AF32==0, EPI==0)
template<int EPI, int RELUA, int KS, int AF32, int OF32, int KQ>
__global__ __launch_bounds__(256) void gemm_k(
    const void* __restrict__ A_, const float* __restrict__ W,
    const float* __restrict__ bias, void* __restrict__ C_,
    const float* __restrict__ asrc, const float* __restrict__ wqt,
    float* __restrict__ kdot, float* __restrict__ qdot, int M, int N)
{
  const int lane = threadIdx.x & 63;
  const int wave = threadIdx.x >> 6;
  const int quad = lane >> 4;
  const int l16  = lane & 15;
  const int n0   = blockIdx.y * 64 + wave * 16;
  if (n0 >= N) return;

  short8 bfrag[KS];
#pragma unroll
  for (int ks = 0; ks < KS; ++ks) {
    short8 bf;
    const int kb = ks * 32 + quad * 8;
#pragma unroll
    for (int j = 0; j < 8; ++j)
      bf[j] = (short)f2b(W[(size_t)(kb + j) * N + n0 + l16]);
    bfrag[ks] = bf;
  }
  float bv = 0.f;
  if (EPI == 2 || EPI == 3) bv = bias[n0 + l16];

  const int mtiles = M >> 4;
  for (int mt = blockIdx.x; mt < mtiles; mt += gridDim.x) {
    f32x4 acc = {0.f, 0.f, 0.f, 0.f};
    float qp[4] = {0.f, 0.f, 0.f, 0.f};
    if (AF32) {
      const float* arow = (const float*)A_ + (size_t)(mt * 16 + l16) * (KS * 32);
#pragma unroll
      for (int ks = 0; ks < KS; ++ks) {
        short8 af;
#pragma unroll
        for (int j = 0; j < 8; ++j) {
          float v = arow[ks * 32 + quad * 8 + j];
          if (RELUA) v = fmaxf(v, 0.f);
          af[j] = (short)f2b(v);
        }
        acc = __builtin_amdgcn_mfma_f32_16x16x32_bf16(af, bfrag[ks], acc, 0, 0, 0);
      }
    } else {
      const u16* arow = (const u16*)A_ + (size_t)(mt * 16 + l16) * (KS * 32);
#pragma unroll
      for (int ks = 0; ks < KS; ++ks) {
        short8 af = *(const short8*)(arow + ks * 32 + quad * 8);
        if (RELUA) {
#pragma unroll
          for (int j = 0; j < 8; ++j) af[j] = (af[j] < (short)0) ? (short)0 : af[j];
        }
        if (KQ) {
#pragma unroll
          for (int j = 0; j < 8; ++j) {
            float v = b2f((u16)af[j]);
            const float* wr = wqt + (size_t)(ks * 32 + quad * 8 + j) * 4;
            qp[0] += v * wr[0]; qp[1] += v * wr[1];
            qp[2] += v * wr[2]; qp[3] += v * wr[3];
          }
        }
        acc = __builtin_amdgcn_mfma_f32_16x16x32_bf16(af, bfrag[ks], acc, 0, 0, 0);
      }
    }

    if (KQ) {
      // qdot[row] = full-K sum: reduce partials across the 4 quads
#pragma unroll
      for (int h = 0; h < 4; ++h) {
        qp[h] += __shfl_xor(qp[h], 16, 64);
        qp[h] += __shfl_xor(qp[h], 32, 64);
      }
      if (blockIdx.y == 0 && quad == 0) {
        f32x4 qv; qv[0] = qp[0]; qv[1] = qp[1]; qv[2] = qp[2]; qv[3] = qp[3];
        *(f32x4*)(qdot + (size_t)(mt * 16 + l16) * 4) = qv;
      }
      // kdot[row][h] partial over this wave's 16 cols: reduce across l16, one atomic
      const int hh = n0 >> 5;
      const float asv = asrc[n0 + l16];
#pragma unroll
      for (int r = 0; r < 4; ++r) {
        float sr = acc[r] * asv;
        sr += __shfl_xor(sr, 1, 64); sr += __shfl_xor(sr, 2, 64);
        sr += __shfl_xor(sr, 4, 64); sr += __shfl_xor(sr, 8, 64);
        if (l16 == 0)
          atomicAdd(&kdot[(size_t)(mt * 16 + quad * 4 + r) * 4 + hh], sr);
      }
    }

#pragma unroll
    for (int r = 0; r < 4; ++r) {
      float v = acc[r];
      if (EPI == 2)      { v += bv; v = (v > 0.f) ? v : 0.2f * v; }
      else if (EPI == 3) { v += bv; }
      const size_t idx = (size_t)(mt * 16 + quad * 4 + r) * N + n0 + l16;
      if (OF32) ((float*)C_)[idx] = v;
      else      ((u16*)C_)[idx] = f2b(v);
    }
  }
}

// ---------- fused rnn GEMM: out = tanh( cvt(A1 fp32)@W1 + A2@W2 ), N=128 ----------
__global__ __launch_bounds__(256) void gemm2_k(
    const float* __restrict__ A1, const u16* __restrict__ W1,
    const u16* __restrict__ A2, const u16* __restrict__ W2,
    u16* __restrict__ Cout, int M)
{
  const int lane = threadIdx.x & 63;
  const int wave = threadIdx.x >> 6;
  const int quad = lane >> 4;
  const int l16  = lane & 15;
  const int n0   = blockIdx.y * 64 + wave * 16;   // N fixed 128, grid.y==2

  short8 bf1[4], bf2[4];
#pragma unroll
  for (int ks = 0; ks < 4; ++ks) {
    short8 a, b;
    const int kb = ks * 32 + quad * 8;
#pragma unroll
    for (int j = 0; j < 8; ++j) {
      a[j] = (short)W1[(size_t)(kb + j) * HC_ + n0 + l16];
      b[j] = (short)W2[(size_t)(kb + j) * HC_ + n0 + l16];
    }
    bf1[ks] = a; bf2[ks] = b;
  }

  const int mtiles = M >> 4;
  for (int mt = blockIdx.x; mt < mtiles; mt += gridDim.x) {
    const int rowm = mt * 16 + l16;
    const float* a1 = A1 + (size_t)rowm * HC_;
    const u16*   a2 = A2 + (size_t)rowm * HC_;
    f32x4 acc = {0.f, 0.f, 0.f, 0.f};
#pragma unroll
    for (int ks = 0; ks < 4; ++ks) {
      short8 af;
      const float* p = a1 + ks * 32 + quad * 8;
#pragma unroll
      for (int j = 0; j < 8; ++j) af[j] = (short)f2b(p[j]);
      acc = __builtin_amdgcn_mfma_f32_16x16x32_bf16(af, bf1[ks], acc, 0, 0, 0);
    }
#pragma unroll
    for (int ks = 0; ks < 4; ++ks) {
      short8 af = *(const short8*)(a2 + ks * 32 + quad * 8);
      acc = __builtin_amdgcn_mfma_f32_16x16x32_bf16(af, bf2[ks], acc, 0, 0, 0);
    }
#pragma unroll
    for (int r = 0; r < 4; ++r)
      Cout[(size_t)(mt * 16 + quad * 4 + r) * HC_ + n0 + l16] = f2b(tanhf(acc[r]));
  }
}

// ========= fused conv: per-dst gather over fixed-cap buckets; LDS alpha cache ==========
// One wave per destination node; lane handles channels {lane, lane+64}.
template<int MASKED>
__global__ __launch_bounds__(256) void conv_k(
    const int* __restrict__ cur, const int2* __restrict__ meta,
    const f32x4* __restrict__ edot,
    const u16* __restrict__ kbuf,
    const float* __restrict__ kdot, const float* __restrict__ qdot,
    const float* __restrict__ uemb, const float* __restrict__ iemb,
    const float* __restrict__ temb,
    const float* __restrict__ udemb, const float* __restrict__ idemb,
    const int* __restrict__ center, float* __restrict__ CO, int Ncnt)
{
  __shared__ float als[4][CAP][4];
  const int wv = threadIdx.x >> 6;
  int wid = (blockIdx.x * blockDim.x + threadIdx.x) >> 6;
  if (wid >= Ncnt) return;
  const int lane = threadIdx.x & 63;
  const int n = MASKED ? center[wid] : wid;
  int cnt = cur[n]; if (cnt > CAP) cnt = CAP;
  const int h0 = lane >> 5;       // head of channel lane     (0 or 1)
  const int h1 = h0 + 2;          // head of channel lane+64  (2 or 3)
  const float q0 = qdot[n * 4 + h0];
  const float q1 = qdot[n * 4 + h1];
  const int2* mb = meta + (size_t)n * CAP;
  const f32x4* eb = edot + (size_t)n * CAP;

  float den0 = 0.f, den1 = 0.f;
  for (int e = 0; e < cnt; ++e) {
    int s = mb[e].x;
    f32x4 ed = eb[e];
    float l0 = kdot[s * 4 + h0] + q0 + ed[h0];
    float l1 = kdot[s * 4 + h1] + q1 + ed[h1];
    l0 = (l0 > 0.f) ? l0 : 0.2f * l0;
    l1 = (l1 > 0.f) ? l1 : 0.2f * l1;
    float a0 = __expf(fminf(l0, 30.f));
    float a1 = __expf(fminf(l1, 30.f));
    den0 += a0; den1 += a1;
    if ((lane & 31) == 0) { als[wv][e][h0] = a0; als[wv][e][h1] = a1; }
  }
  const float r0 = 1.f / fmaxf(den0, 1e-16f);
  const float r1 = 1.f / fmaxf(den1, 1e-16f);

  float acc0 = 0.f, acc1 = 0.f;
  for (int e = 0; e < cnt; ++e) {
    int2 mrec = mb[e];
    int s = mrec.x;
    int ty = mrec.y & 7, to = (mrec.y >> 3) & 1023, di = mrec.y >> 13;
    float al0 = als[wv][e][h0] * r0;
    float al1 = als[wv][e][h1] * r1;

    float m0 = b2f(kbuf[(size_t)s * HC_ + lane]);
    float m1 = b2f(kbuf[(size_t)s * HC_ + 64 + lane]);
    const float* et = (ty == 0) ? uemb : (ty < 2) ? iemb : temb;
    m0 += et[(size_t)to * HC_ + lane];
    m1 += et[(size_t)to * HC_ + 64 + lane];
    if (ty == 0 || ty == 2 || ty == 3) {
      const float* dt = (ty == 0) ? udemb : idemb;
      m0 += dt[(size_t)di * HC_ + lane];
      m1 += dt[(size_t)di * HC_ + 64 + lane];
    }
    acc0 += al0 * m0;
    acc1 += al1 * m1;
  }
  CO[(size_t)n * HC_ + lane]      = acc0;
  CO[(size_t)n * HC_ + 64 + lane] = acc1;
}

// ========= merged h2 + pred-head layer 1 (one block per 16-row m-tile of B) ===========
// Phase G: h2 = tanh(CO[nid]@rnn_top + relu(h1[nid])@rnn_bot)  -> LDS
// Phase H: hdd = lrelu([x|h1|h2][center] @ w1 + b1)
__global__ __launch_bounds__(256) void gh_k(
    const float* __restrict__ CO, const u16* __restrict__ rnn_wb,
    const u16* __restrict__ h1, const u16* __restrict__ xb,
    const int* __restrict__ center, const float* __restrict__ w1,
    const float* __restrict__ b1, u16* __restrict__ hdd)
{
  __shared__ u16 h2s[16][136];   // +8 pad: 272B row stride (16B-aligned, low conflict)
  const int t = threadIdx.x;
  const int lane = t & 63, wave = t >> 6, quad = lane >> 4, l16 = lane & 15;
  const int mt = blockIdx.x;
  const int rowm = mt * 16 + l16;
  const int nid = center[rowm];
  const u16* W1 = rnn_wb;                 // rnn top half (rows 0..127)
  const u16* W2 = rnn_wb + HC_ * HC_;     // rnn bottom half

  // ---- phase G ----
#pragma unroll
  for (int half = 0; half < 2; ++half) {
    const int n0 = half * 64 + wave * 16;
    short8 bf1[4], bf2[4];
#pragma unroll
    for (int ks = 0; ks < 4; ++ks) {
      short8 a, b;
      const int kb = ks * 32 + quad * 8;
#pragma unroll
      for (int j = 0; j < 8; ++j) {
        a[j] = (short)W1[(size_t)(kb + j) * HC_ + n0 + l16];
        b[j] = (short)W2[(size_t)(kb + j) * HC_ + n0 + l16];
      }
      bf1[ks] = a; bf2[ks] = b;
    }
    const float* a1 = CO + (size_t)nid * HC_;
    const u16*   a2 = h1 + (size_t)nid * HC_;
    f32x4 acc = {0.f, 0.f, 0.f, 0.f};
#pragma unroll
    for (int ks = 0; ks < 4; ++ks) {
      short8 af;
      const float* p = a1 + ks * 32 + quad * 8;
#pragma unroll
      for (int j = 0; j < 8; ++j) af[j] = (short)f2b(p[j]);
      acc = __builtin_amdgcn_mfma_f32_16x16x32_bf16(af, bf1[ks], acc, 0, 0, 0);
    }
#pragma unroll
    for (int ks = 0; ks < 4; ++ks) {
      short8 af = *(const short8*)(a2 + ks * 32 + quad * 8);
#pragma unroll
      for (int j = 0; j < 8; ++j) af[j] = (af[j] < (short)0) ? (short)0 : af[j];
      acc = __builtin_amdgcn_mfma_f32_16x16x32_bf16(af, bf2[ks], acc, 0, 0, 0);
    }
#pragma unroll
    for (int r = 0; r < 4; ++r)
      h2s[quad * 4 + r][n0 + l16] = f2b(tanhf(acc[r]));
  }
  __syncthreads();

  // ---- phase H ----
#pragma unroll
  for (int half = 0; half < 2; ++half) {
    const int n0 = half * 64 + wave * 16;
    short8 bfrag[12];
#pragma unroll
    for (int ks = 0; ks < 12; ++ks) {
      short8 bf;
      const int kb = ks * 32 + quad * 8;
#pragma unroll
      for (int j = 0; j < 8; ++j)
        bf[j] = (short)f2b(w1[(size_t)(kb + j) * HC_ + n0 + l16]);
      bfrag[ks] = bf;
    }
    const float bv = b1[n0 + l16];
    f32x4 acc = {0.f, 0.f, 0.f, 0.f};
#pragma unroll
    for (int ks = 0; ks < 12; ++ks) {
      short8 af;
      if (ks < 4)
        af = *(const short8*)(xb + (size_t)nid * HC_ + ks * 32 + quad * 8);
      else if (ks < 8)
        af = *(const short8*)(h1 + (size_t)nid * HC_ + (ks - 4) * 32 + quad * 8);
      else
        af = *(const short8*)(&h2s[l16][(ks - 8) * 32 + quad * 8]);
      acc = __builtin_amdgcn_mfma_f32_16x16x32_bf16(af, bfrag[ks], acc, 0, 0, 0);
    }
#pragma unroll
    for (int r = 0; r < 4; ++r) {
      float v = acc[r] + bv;
      v = (v > 0.f) ? v : 0.2f * v;
      hdd[(size_t)(mt * 16 + quad * 4 + r) * HC_ + n0 + l16] = f2b(v);
    }
  }
}

// =======================================================================
extern "C" void kernel_launch(void* const* d_in, const int* in_sizes, int n_in,
                              void* d_out, int out_size, void* d_ws, size_t ws_size,
                              hipStream_t stream)
{
  (void)n_in; (void)out_size; (void)ws_size;
  const int* node_idx = (const int*)d_in[0];
  const int* eidx     = (const int*)d_in[1];
  const int* etype    = (const int*)d_in[2];
  const int* toff0    = (const int*)d_in[3];
  const int* toff1    = (const int*)d_in[4];
  const int* dist0    = (const int*)d_in[5];
  const int* dist1    = (const int*)d_in[6];
  const int* center   = (const int*)d_in[7];
  const float* id_emb   = (const float*)d_in[8];
  const float* u_att    = (const float*)d_in[9];
  const float* i_att    = (const float*)d_in[10];
  const float* t_att    = (const float*)d_in[11];
  const float* u_emb    = (const float*)d_in[12];
  const float* i_emb    = (const float*)d_in[13];
  const float* t_emb    = (const float*)d_in[14];
  const float* u_att2   = (const float*)d_in[15];
  const float* i_att2   = (const float*)d_in[16];
  const float* t_att2   = (const float*)d_in[17];
  const float* u_emb2   = (const float*)d_in[18];
  const float* i_emb2   = (const float*)d_in[19];
  const float* t_emb2   = (const float*)d_in[20];
  const float* ud_att   = (const float*)d_in[21];
  const float* id_att   = (const float*)d_in[22];
  const float* ud_emb   = (const float*)d_in[23];
  const float* id_embd  = (const float*)d_in[24];
  const float* ud_att2  = (const float*)d_in[25];
  const float* id_att2  = (const float*)d_in[26];
  const float* ud_emb2  = (const float*)d_in[27];
  const float* id_emb2  = (const float*)d_in[28];
  const float* trans_head = (const float*)d_in[29];
  const float* rnn_w    = (const float*)d_in[30];
  const float* w1       = (const float*)d_in[31];
  const float* b1       = (const float*)d_in[32];
  const float* w2       = (const float*)d_in[33];
  const float* b2       = (const float*)d_in[34];
  const float* wl0      = (const float*)d_in[35];
  const float* wr0      = (const float*)d_in[36];
  const float* asrc0    = (const float*)d_in[37];
  const float* adst0    = (const float*)d_in[38];
  const float* wl1      = (const float*)d_in[39];
  const float* wr1      = (const float*)d_in[40];
  const float* asrc1    = (const float*)d_in[41];
  const float* adst1    = (const float*)d_in[42];

  const int N_    = in_sizes[0];
  const int E_    = in_sizes[2];
  const int B_    = in_sizes[7];
  const int ITEM_ = in_sizes[34];
  const int* esrc = eidx;
  const int* edst = eidx + E_;

  // ---- workspace carve-up (256B aligned), ~155 MB ----
  char* ws = (char*)d_ws;
  size_t off = 0;
  auto alloc = [&](size_t bytes) -> char* {
    char* p = ws + off;
    off += (bytes + 255) & ~(size_t)255;
    return p;
  };
  float* CO_b  = (float*)alloc((size_t)N_ * HC_ * 4);   // 25.6M
  u16*   k_b   = (u16*)  alloc((size_t)N_ * HC_ * 2);   // 12.8M
  u16*   x_b   = (u16*)  alloc((size_t)N_ * HC_ * 2);   // 12.8M
  u16*   h1_b  = (u16*)  alloc((size_t)N_ * HC_ * 2);   // 12.8M
  float* kdot0 = (float*)alloc((size_t)N_ * 4 * 4);
  float* kdot1 = (float*)alloc((size_t)N_ * 4 * 4);
  float* qdot  = (float*)alloc((size_t)N_ * 4 * 4);
  float* dots  = (float*)alloc((size_t)DOT_ROWS * 4 * 4);
  float* wq    = (float*)alloc(1024 * 4);               // wq0 | wq1
  u16*   rnn_wb= (u16*)  alloc(256 * HC_ * 2);          // bf16 copy of rnn_w
  u16*   Wt    = (u16*)  alloc(HC_ * HC_ * 2);          // bf16(trans_head @ rnn_w_bot)
  u16*   hdd   = (u16*)  alloc((size_t)B_ * HC_ * 2);
  int*   cur   = (int*)  alloc((size_t)N_ * 4);         // bucket counts
  int2*  m0a   = (int2*) alloc((size_t)N_ * CAP * 8);   // 12.8M
  int2*  m1a   = (int2*) alloc((size_t)N_ * CAP * 8);   // 12.8M
  f32x4* e0a   = (f32x4*)alloc((size_t)N_ * CAP * 16);  // 25.6M
  f32x4* e1a   = (f32x4*)alloc((size_t)N_ * CAP * 16);  // 25.6M

  const int TB = 256;
  auto nb = [&](long long t) { return (int)((t + TB - 1) / TB); };

  // 1) fused prolog (zero cur/kdot0/kdot1, gather x, dots, wq, cvt rnn, Wt)
  const int nbCur  = (N_ + 255) / 256;
  const int nbKd   = (N_ * 4 + 255) / 256;
  const int nbGx   = (N_ * 16 + 255) / 256;
  const int nbDots = (DOT_ROWS * 4 + 255) / 256;
  const int prologBlocks = nbCur + nbKd + nbGx + nbDots + 4 + 128 + 64;
  prolog_k<<<prologBlocks, TB, 0, stream>>>(
      node_idx, id_emb, x_b,
      u_att, i_att, t_att, ud_att, id_att,
      u_att2, i_att2, t_att2, ud_att2, id_att2,
      asrc0, asrc1, dots,
      wr0, adst0, wr1, adst1, wq,
      rnn_w, rnn_wb, trans_head, Wt,
      cur, kdot0, kdot1, N_);

  // 2) bucket fill (SoA; pre-sums edge att-dots for both layers)
  fill_k<<<nb(E_), TB, 0, stream>>>(esrc, edst, etype, toff0, toff1, dist0, dist1,
                                    dots, cur, m0a, e0a, m1a, e1a, E_);

  // 3) layer 0: k0 = x @ wl0 with fused kdot0/qdot epilogue
  gemm_k<0,0,4,0,0,1><<<dim3(640, 2), TB, 0, stream>>>(
      x_b, wl0, nullptr, k_b, asrc0, wq, kdot0, qdot, N_, HC_);

  // 4) layer-0 fused attention+aggregate
  conv_k<0><<<nb((long long)N_ * 64), TB, 0, stream>>>(
      cur, m0a, e0a, k_b, kdot0, qdot,
      u_emb, i_emb, t_emb, ud_emb, id_embd, nullptr, CO_b, N_);

  // 5) h1 = tanh(CO @ rnn_w_top + x @ Wt)
  gemm2_k<<<dim3(640, 2), TB, 0, stream>>>(CO_b, rnn_wb, x_b, Wt, h1_b, N_);

  // 6) layer 1: k1 = relu(h1) @ wl1 with fused kdot1/qdot epilogue
  gemm_k<0,1,4,0,0,1><<<dim3(640, 2), TB, 0, stream>>>(
      h1_b, wl1, nullptr, k_b, asrc1, wq + 512, kdot1, qdot, N_, HC_);

  // 7) layer-1 fused attention+aggregate, center nodes only
  conv_k<1><<<nb((long long)B_ * 64), TB, 0, stream>>>(
      cur, m1a, e1a, k_b, kdot1, qdot,
      u_emb2, i_emb2, t_emb2, ud_emb2, id_emb2, center, CO_b, B_);

  // 8) merged: h2 (LDS) + hdd = lrelu([x|h1|h2][center] @ w1 + b1)
  gh_k<<<B_ / 16, TB, 0, stream>>>(CO_b, rnn_wb, h1_b, x_b, center, w1, b1, hdd);

  // 9) logits = hdd @ w2 + b2 -> d_out (fp32); w2 staged exactly once (grid.x=1)
  gemm_k<3,0,4,0,1,0><<<dim3(1, (ITEM_ + 63) / 64), TB, 0, stream>>>(
      hdd, w2, b2, d_out, nullptr, nullptr, nullptr, nullptr, B_, ITEM_);
}

// Round 5
// 634.786 us; speedup vs baseline: 1.0707x; 1.0707x over previous
//
#include <hip/hip_runtime.h>
#include <cstdint>
#include <cstddef>

typedef unsigned short u16;
typedef __attribute__((ext_vector_type(8))) short short8;
typedef __attribute__((ext_vector_type(4))) float f32x4;

// ---------- constants (match reference) ----------
#define HC_ 128
#define CAP 32            // in-degree bucket capacity (Poisson(4) tail ~1e-18)
// dot-table row offsets (rows of 4 floats)
#define OFF_U0   0
#define OFF_I0   202
#define OFF_T0   404
#define OFF_UD0  606
#define OFF_ID0  1107
#define OFF_U2   1608
#define OFF_I2   2410
#define OFF_T2   3212
#define OFF_UD2  4014
#define OFF_ID2  4515
#define DOT_ROWS 5016

__device__ __forceinline__ float b2f(u16 u) {
  union { unsigned int i; float f; } v; v.i = ((unsigned int)u) << 16; return v.f;
}
__device__ __forceinline__ u16 f2b(float f) {
  union { float f; unsigned int i; } v; v.f = f;
  unsigned int r = v.i + 0x7fffu + ((v.i >> 16) & 1u);
  return (u16)(r >> 16);
}

// ================= fused prolog: zero cur/kdot, gather x, dots, wq, cvt rnn, Wt ========
__global__ __launch_bounds__(256) void prolog_k(
    const int* __restrict__ nidx, const float* __restrict__ emb, u16* __restrict__ x,
    const float* u0, const float* i0, const float* t0, const float* ud0, const float* id0,
    const float* u2, const float* i2, const float* t2, const float* ud2, const float* id2,
    const float* __restrict__ asrc0, const float* __restrict__ asrc1,
    float* __restrict__ dots,
    const float* __restrict__ wr0, const float* __restrict__ adst0,
    const float* __restrict__ wr1, const float* __restrict__ adst1,
    float* __restrict__ wq,
    const float* __restrict__ rnn_w, u16* __restrict__ rnn_wb,
    const float* __restrict__ th, u16* __restrict__ Wt,
    int* __restrict__ cur, float* __restrict__ kdot0, float* __restrict__ kdot1, int Nn)
{
  int b = blockIdx.x, t = threadIdx.x;
  const int nbCur  = (Nn + 255) >> 8;
  const int nbKd   = (Nn * 4 + 255) >> 8;
  const int nbGx   = (Nn * 16 + 255) >> 8;
  const int nbDots = (DOT_ROWS * 4 + 255) >> 8;

  if (b < nbCur) { int i = b * 256 + t; if (i < Nn) cur[i] = 0; return; }
  b -= nbCur;
  if (b < nbKd) {
    int i = b * 256 + t;
    if (i < Nn * 4) { kdot0[i] = 0.f; kdot1[i] = 0.f; }
    return;
  }
  b -= nbKd;
  if (b < nbGx) {  // x = bf16(id_emb[node_idx])
    int i = b * 256 + t;
    int n = i >> 4, c = (i & 15) << 3;
    if (n < Nn) {
      int id = nidx[n];
      const float* s = emb + (size_t)id * HC_ + c;
      u16 tmp[8];
#pragma unroll
      for (int j = 0; j < 8; ++j) tmp[j] = f2b(s[j]);
      *(short8*)(x + (size_t)n * HC_ + c) = *(short8*)tmp;
    }
    return;
  }
  b -= nbGx;
  if (b < nbDots) {  // att-bias dot tables
    int i = b * 256 + t;
    if (i < DOT_ROWS * 4) {
      int r = i >> 2, h = i & 3;
      const float* tab; int lr; const float* as;
      if      (r < OFF_I0)  { tab = u0;  lr = r;            as = asrc0; }
      else if (r < OFF_T0)  { tab = i0;  lr = r - OFF_I0;   as = asrc0; }
      else if (r < OFF_UD0) { tab = t0;  lr = r - OFF_T0;   as = asrc0; }
      else if (r < OFF_ID0) { tab = ud0; lr = r - OFF_UD0;  as = asrc0; }
      else if (r < OFF_U2)  { tab = id0; lr = r - OFF_ID0;  as = asrc0; }
      else if (r < OFF_I2)  { tab = u2;  lr = r - OFF_U2;   as = asrc1; }
      else if (r < OFF_T2)  { tab = i2;  lr = r - OFF_I2;   as = asrc1; }
      else if (r < OFF_UD2) { tab = t2;  lr = r - OFF_T2;   as = asrc1; }
      else if (r < OFF_ID2) { tab = ud2; lr = r - OFF_UD2;  as = asrc1; }
      else                  { tab = id2; lr = r - OFF_ID2;  as = asrc1; }
      float s = 0.f;
#pragma unroll
      for (int c = 0; c < 32; ++c)
        s += tab[(size_t)lr * HC_ + h * 32 + c] * as[h * 32 + c];
      dots[i] = s;
    }
    return;
  }
  b -= nbDots;
  if (b < 4) {  // wq[layer][k][h]
    int i = b * 256 + t;
    int layer = i >> 9, k = (i >> 2) & 127, h = i & 3;
    const float* wr = layer ? wr1 : wr0;
    const float* ad = layer ? adst1 : adst0;
    float s = 0.f;
#pragma unroll
    for (int c = 0; c < 32; ++c)
      s += wr[(size_t)k * HC_ + h * 32 + c] * ad[h * 32 + c];
    wq[i] = s;
    return;
  }
  b -= 4;
  if (b < 128) {  // rnn_w -> bf16
    int i = b * 256 + t;
    rnn_wb[i] = f2b(rnn_w[i]);
    return;
  }
  b -= 128;
  {  // Wt = bf16(trans_head @ rnn_w[128:,:]), 16384 outputs
    int i = b * 256 + t;
    if (i < 16384) {
      int r = i >> 7, c = i & 127;
      float s = 0.f;
#pragma unroll 8
      for (int k = 0; k < 128; ++k)
        s += th[r * 128 + k] * rnn_w[(size_t)(128 + k) * 128 + c];
      Wt[i] = f2b(s);
    }
  }
}

// ================= bucket fill (SoA): meta {src, ty|to<<3|di<<13} + edot f32x4 =========
__global__ void fill_k(const int* __restrict__ src, const int* __restrict__ dst,
                       const int* __restrict__ ety,
                       const int* __restrict__ toff0, const int* __restrict__ toff1,
                       const int* __restrict__ dist0, const int* __restrict__ dist1,
                       const float* __restrict__ dots,
                       int* __restrict__ cur,
                       int2* __restrict__ m0a, f32x4* __restrict__ e0a,
                       int2* __restrict__ m1a, f32x4* __restrict__ e1a, int E)
{
  int e = blockIdx.x * blockDim.x + threadIdx.x;
  if (e >= E) return;
  int d = dst[e];
  int slot = atomicAdd(&cur[d], 1);
  if (slot >= CAP) return;   // statistically unreachable
  int s = src[e], ty = ety[e];
  int to0 = toff0[e], to1 = toff1[e], di0 = dist0[e], di1 = dist1[e];
  bool inv = (ty == 0 || ty == 2 || ty == 3);
  int ar0 = (ty == 0) ? (OFF_U0 + to0) : (ty < 2) ? (OFF_I0 + to0) : (OFF_T0 + to0);
  int ar1 = (ty == 0) ? (OFF_U2 + to1) : (ty < 2) ? (OFF_I2 + to1) : (OFF_T2 + to1);
  f32x4 e0 = *(const f32x4*)(dots + (size_t)ar0 * 4);
  f32x4 e1 = *(const f32x4*)(dots + (size_t)ar1 * 4);
  if (inv) {
    int dr0 = ((ty == 0) ? OFF_UD0 : OFF_ID0) + di0;
    int dr1 = ((ty == 0) ? OFF_UD2 : OFF_ID2) + di1;
    e0 += *(const f32x4*)(dots + (size_t)dr0 * 4);
    e1 += *(const f32x4*)(dots + (size_t)dr1 * 4);
  }
  size_t ix = (size_t)d * CAP + slot;
  m0a[ix] = make_int2(s, ty | (to0 << 3) | (di0 << 13));
  m1a[ix] = make_int2(s, ty | (to1 << 3) | (di1 << 13));
  e0a[ix] = e0;
  e1a[ix] = e1;
}

// ---------- generic MFMA GEMM: C[M,N] = epi(A[M,K] @ W[K,N]) ----------
// KQ: fused kdot/qdot epilogue (requires N==128, AF32==0, EPI==0)
template<int EPI, int RELUA, int KS, int AF32, int OF32, int KQ>
__global__ __launch_bounds__(256) void gemm_k(
    const void* __restrict__ A_, const float* __restrict__ W,
    const float* __restrict__ bias, void* __restrict__ C_,
    const float* __restrict__ asrc, const float* __restrict__ wqt,
    float* __restrict__ kdot, float* __restrict__ qdot, int M, int N)
{
  const int lane = threadIdx.x & 63;
  const int wave = threadIdx.x >> 6;
  const int quad = lane >> 4;
  const int l16  = lane & 15;
  const int n0   = blockIdx.y * 64 + wave * 16;
  if (n0 >= N) return;

  short8 bfrag[KS];
#pragma unroll
  for (int ks = 0; ks < KS; ++ks) {
    short8 bf;
    const int kb = ks * 32 + quad * 8;
#pragma unroll
    for (int j = 0; j < 8; ++j)
      bf[j] = (short)f2b(W[(size_t)(kb + j) * N + n0 + l16]);
    bfrag[ks] = bf;
  }
  float bv = 0.f;
  if (EPI == 2 || EPI == 3) bv = bias[n0 + l16];

  const int mtiles = M >> 4;
  for (int mt = blockIdx.x; mt < mtiles; mt += gridDim.x) {
    f32x4 acc = {0.f, 0.f, 0.f, 0.f};
    float qp[4] = {0.f, 0.f, 0.f, 0.f};
    if (AF32) {
      const float* arow = (const float*)A_ + (size_t)(mt * 16 + l16) * (KS * 32);
#pragma unroll
      for (int ks = 0; ks < KS; ++ks) {
        short8 af;
#pragma unroll
        for (int j = 0; j < 8; ++j) {
          float v = arow[ks * 32 + quad * 8 + j];
          if (RELUA) v = fmaxf(v, 0.f);
          af[j] = (short)f2b(v);
        }
        acc = __builtin_amdgcn_mfma_f32_16x16x32_bf16(af, bfrag[ks], acc, 0, 0, 0);
      }
    } else {
      const u16* arow = (const u16*)A_ + (size_t)(mt * 16 + l16) * (KS * 32);
#pragma unroll
      for (int ks = 0; ks < KS; ++ks) {
        short8 af = *(const short8*)(arow + ks * 32 + quad * 8);
        if (RELUA) {
#pragma unroll
          for (int j = 0; j < 8; ++j) af[j] = (af[j] < (short)0) ? (short)0 : af[j];
        }
        if (KQ) {
#pragma unroll
          for (int j = 0; j < 8; ++j) {
            float v = b2f((u16)af[j]);
            const float* wr = wqt + (size_t)(ks * 32 + quad * 8 + j) * 4;
            qp[0] += v * wr[0]; qp[1] += v * wr[1];
            qp[2] += v * wr[2]; qp[3] += v * wr[3];
          }
        }
        acc = __builtin_amdgcn_mfma_f32_16x16x32_bf16(af, bfrag[ks], acc, 0, 0, 0);
      }
    }

    if (KQ) {
      // qdot[row] = full-K sum: reduce partials across the 4 quads
#pragma unroll
      for (int h = 0; h < 4; ++h) {
        qp[h] += __shfl_xor(qp[h], 16, 64);
        qp[h] += __shfl_xor(qp[h], 32, 64);
      }
      if (blockIdx.y == 0 && quad == 0) {
        f32x4 qv; qv[0] = qp[0]; qv[1] = qp[1]; qv[2] = qp[2]; qv[3] = qp[3];
        *(f32x4*)(qdot + (size_t)(mt * 16 + l16) * 4) = qv;
      }
      // kdot[row][h] partial over this wave's 16 cols: reduce across l16, one atomic
      const int hh = n0 >> 5;
      const float asv = asrc[n0 + l16];
#pragma unroll
      for (int r = 0; r < 4; ++r) {
        float sr = acc[r] * asv;
        sr += __shfl_xor(sr, 1, 64); sr += __shfl_xor(sr, 2, 64);
        sr += __shfl_xor(sr, 4, 64); sr += __shfl_xor(sr, 8, 64);
        if (l16 == 0)
          atomicAdd(&kdot[(size_t)(mt * 16 + quad * 4 + r) * 4 + hh], sr);
      }
    }

#pragma unroll
    for (int r = 0; r < 4; ++r) {
      float v = acc[r];
      if (EPI == 2)      { v += bv; v = (v > 0.f) ? v : 0.2f * v; }
      else if (EPI == 3) { v += bv; }
      const size_t idx = (size_t)(mt * 16 + quad * 4 + r) * N + n0 + l16;
      if (OF32) ((float*)C_)[idx] = v;
      else      ((u16*)C_)[idx] = f2b(v);
    }
  }
}

// ---------- fused rnn GEMM: out = tanh( cvt(A1 fp32)@W1 + A2@W2 ), N=128 ----------
__global__ __launch_bounds__(256) void gemm2_k(
    const float* __restrict__ A1, const u16* __restrict__ W1,
    const u16* __restrict__ A2, const u16* __restrict__ W2,
    u16* __restrict__ Cout, int M)
{
  const int lane = threadIdx.x & 63;
  const int wave = threadIdx.x >> 6;
  const int quad = lane >> 4;
  const int l16  = lane & 15;
  const int n0   = blockIdx.y * 64 + wave * 16;   // N fixed 128, grid.y==2

  short8 bf1[4], bf2[4];
#pragma unroll
  for (int ks = 0; ks < 4; ++ks) {
    short8 a, b;
    const int kb = ks * 32 + quad * 8;
#pragma unroll
    for (int j = 0; j < 8; ++j) {
      a[j] = (short)W1[(size_t)(kb + j) * HC_ + n0 + l16];
      b[j] = (short)W2[(size_t)(kb + j) * HC_ + n0 + l16];
    }
    bf1[ks] = a; bf2[ks] = b;
  }

  const int mtiles = M >> 4;
  for (int mt = blockIdx.x; mt < mtiles; mt += gridDim.x) {
    const int rowm = mt * 16 + l16;
    const float* a1 = A1 + (size_t)rowm * HC_;
    const u16*   a2 = A2 + (size_t)rowm * HC_;
    f32x4 acc = {0.f, 0.f, 0.f, 0.f};
#pragma unroll
    for (int ks = 0; ks < 4; ++ks) {
      short8 af;
      const float* p = a1 + ks * 32 + quad * 8;
#pragma unroll
      for (int j = 0; j < 8; ++j) af[j] = (short)f2b(p[j]);
      acc = __builtin_amdgcn_mfma_f32_16x16x32_bf16(af, bf1[ks], acc, 0, 0, 0);
    }
#pragma unroll
    for (int ks = 0; ks < 4; ++ks) {
      short8 af = *(const short8*)(a2 + ks * 32 + quad * 8);
      acc = __builtin_amdgcn_mfma_f32_16x16x32_bf16(af, bf2[ks], acc, 0, 0, 0);
    }
#pragma unroll
    for (int r = 0; r < 4; ++r)
      Cout[(size_t)(mt * 16 + quad * 4 + r) * HC_ + n0 + l16] = f2b(tanhf(acc[r]));
  }
}

// ========= fused conv: per-dst gather over fixed-cap buckets; LDS alpha cache ==========
// One wave per destination node; lane handles channels {lane, lane+64}.
template<int MASKED>
__global__ __launch_bounds__(256) void conv_k(
    const int* __restrict__ cur, const int2* __restrict__ meta,
    const f32x4* __restrict__ edot,
    const u16* __restrict__ kbuf,
    const float* __restrict__ kdot, const float* __restrict__ qdot,
    const float* __restrict__ uemb, const float* __restrict__ iemb,
    const float* __restrict__ temb,
    const float* __restrict__ udemb, const float* __restrict__ idemb,
    const int* __restrict__ center, float* __restrict__ CO, int Ncnt)
{
  __shared__ float als[4][CAP][4];
  const int wv = threadIdx.x >> 6;
  int wid = (blockIdx.x * blockDim.x + threadIdx.x) >> 6;
  if (wid >= Ncnt) return;
  const int lane = threadIdx.x & 63;
  const int n = MASKED ? center[wid] : wid;
  int cnt = cur[n]; if (cnt > CAP) cnt = CAP;
  const int h0 = lane >> 5;       // head of channel lane     (0 or 1)
  const int h1 = h0 + 2;          // head of channel lane+64  (2 or 3)
  const float q0 = qdot[n * 4 + h0];
  const float q1 = qdot[n * 4 + h1];
  const int2* mb = meta + (size_t)n * CAP;
  const f32x4* eb = edot + (size_t)n * CAP;

  float den0 = 0.f, den1 = 0.f;
  for (int e = 0; e < cnt; ++e) {
    int s = mb[e].x;
    f32x4 ed = eb[e];
    float l0 = kdot[s * 4 + h0] + q0 + ed[h0];
    float l1 = kdot[s * 4 + h1] + q1 + ed[h1];
    l0 = (l0 > 0.f) ? l0 : 0.2f * l0;
    l1 = (l1 > 0.f) ? l1 : 0.2f * l1;
    float a0 = __expf(fminf(l0, 30.f));
    float a1 = __expf(fminf(l1, 30.f));
    den0 += a0; den1 += a1;
    if ((lane & 31) == 0) { als[wv][e][h0] = a0; als[wv][e][h1] = a1; }
  }
  const float r0 = 1.f / fmaxf(den0, 1e-16f);
  const float r1 = 1.f / fmaxf(den1, 1e-16f);

  float acc0 = 0.f, acc1 = 0.f;
  for (int e = 0; e < cnt; ++e) {
    int2 mrec = mb[e];
    int s = mrec.x;
    int ty = mrec.y & 7, to = (mrec.y >> 3) & 1023, di = mrec.y >> 13;
    float al0 = als[wv][e][h0] * r0;
    float al1 = als[wv][e][h1] * r1;

    float m0 = b2f(kbuf[(size_t)s * HC_ + lane]);
    float m1 = b2f(kbuf[(size_t)s * HC_ + 64 + lane]);
    const float* et = (ty == 0) ? uemb : (ty < 2) ? iemb : temb;
    m0 += et[(size_t)to * HC_ + lane];
    m1 += et[(size_t)to * HC_ + 64 + lane];
    if (ty == 0 || ty == 2 || ty == 3) {
      const float* dt = (ty == 0) ? udemb : idemb;
      m0 += dt[(size_t)di * HC_ + lane];
      m1 += dt[(size_t)di * HC_ + 64 + lane];
    }
    acc0 += al0 * m0;
    acc1 += al1 * m1;
  }
  CO[(size_t)n * HC_ + lane]      = acc0;
  CO[(size_t)n * HC_ + 64 + lane] = acc1;
}

// ========= merged h2 + pred-head layer 1 (one block per 16-row m-tile of B) ===========
__global__ __launch_bounds__(256) void gh_k(
    const float* __restrict__ CO, const u16* __restrict__ rnn_wb,
    const u16* __restrict__ h1, const u16* __restrict__ xb,
    const int* __restrict__ center, const float* __restrict__ w1,
    const float* __restrict__ b1, u16* __restrict__ hdd)
{
  __shared__ u16 h2s[16][136];   // +8 pad: 272B row stride (16B-aligned, low conflict)
  const int t = threadIdx.x;
  const int lane = t & 63, wave = t >> 6, quad = lane >> 4, l16 = lane & 15;
  const int mt = blockIdx.x;
  const int rowm = mt * 16 + l16;
  const int nid = center[rowm];
  const u16* W1 = rnn_wb;                 // rnn top half (rows 0..127)
  const u16* W2 = rnn_wb + HC_ * HC_;     // rnn bottom half

  // ---- phase G ----
#pragma unroll
  for (int half = 0; half < 2; ++half) {
    const int n0 = half * 64 + wave * 16;
    short8 bf1[4], bf2[4];
#pragma unroll
    for (int ks = 0; ks < 4; ++ks) {
      short8 a, b;
      const int kb = ks * 32 + quad * 8;
#pragma unroll
      for (int j = 0; j < 8; ++j) {
        a[j] = (short)W1[(size_t)(kb + j) * HC_ + n0 + l16];
        b[j] = (short)W2[(size_t)(kb + j) * HC_ + n0 + l16];
      }
      bf1[ks] = a; bf2[ks] = b;
    }
    const float* a1 = CO + (size_t)nid * HC_;
    const u16*   a2 = h1 + (size_t)nid * HC_;
    f32x4 acc = {0.f, 0.f, 0.f, 0.f};
#pragma unroll
    for (int ks = 0; ks < 4; ++ks) {
      short8 af;
      const float* p = a1 + ks * 32 + quad * 8;
#pragma unroll
      for (int j = 0; j < 8; ++j) af[j] = (short)f2b(p[j]);
      acc = __builtin_amdgcn_mfma_f32_16x16x32_bf16(af, bf1[ks], acc, 0, 0, 0);
    }
#pragma unroll
    for (int ks = 0; ks < 4; ++ks) {
      short8 af = *(const short8*)(a2 + ks * 32 + quad * 8);
#pragma unroll
      for (int j = 0; j < 8; ++j) af[j] = (af[j] < (short)0) ? (short)0 : af[j];
      acc = __builtin_amdgcn_mfma_f32_16x16x32_bf16(af, bf2[ks], acc, 0, 0, 0);
    }
#pragma unroll
    for (int r = 0; r < 4; ++r)
      h2s[quad * 4 + r][n0 + l16] = f2b(tanhf(acc[r]));
  }
  __syncthreads();

  // ---- phase H ----
#pragma unroll
  for (int half = 0; half < 2; ++half) {
    const int n0 = half * 64 + wave * 16;
    short8 bfrag[12];
#pragma unroll
    for (int ks = 0; ks < 12; ++ks) {
      short8 bf;
      const int kb = ks * 32 + quad * 8;
#pragma unroll
      for (int j = 0; j < 8; ++j)
        bf[j] = (short)f2b(w1[(size_t)(kb + j) * HC_ + n0 + l16]);
      bfrag[ks] = bf;
    }
    const float bv = b1[n0 + l16];
    f32x4 acc = {0.f, 0.f, 0.f, 0.f};
#pragma unroll
    for (int ks = 0; ks < 12; ++ks) {
      short8 af;
      if (ks < 4)
        af = *(const short8*)(xb + (size_t)nid * HC_ + ks * 32 + quad * 8);
      else if (ks < 8)
        af = *(const short8*)(h1 + (size_t)nid * HC_ + (ks - 4) * 32 + quad * 8);
      else
        af = *(const short8*)(&h2s[l16][(ks - 8) * 32 + quad * 8]);
      acc = __builtin_amdgcn_mfma_f32_16x16x32_bf16(af, bfrag[ks], acc, 0, 0, 0);
    }
#pragma unroll
    for (int r = 0; r < 4; ++r) {
      float v = acc[r] + bv;
      v = (v > 0.f) ? v : 0.2f * v;
      hdd[(size_t)(mt * 16 + quad * 4 + r) * HC_ + n0 + l16] = f2b(v);
    }
  }
}

// ========= final logits GEMM: out[M,ITEM] = hdd @ w2 + b2, coalesced 256B writes =======
// Each wave owns a 64-col window; per m-tile: 16 MFMAs -> wave-private LDS transpose ->
// stores of 4 rows x 256B-contiguous segments. grid = (MSPLIT, ceil(ITEM/256)).
__global__ __launch_bounds__(256) void gemm_out_k(
    const u16* __restrict__ A, const float* __restrict__ W,
    const float* __restrict__ bias, float* __restrict__ out, int M, int ITEM)
{
  __shared__ float lds[4][16][68];   // per-wave [16 rows][64 cols + 4 pad]
  const int lane = threadIdx.x & 63;
  const int wv   = threadIdx.x >> 6;
  const int quad = lane >> 4;
  const int l16  = lane & 15;
  const int nbase = blockIdx.y * 256 + wv * 64;

  // stage B fragments: 4 n-subtiles x 4 k-slices (col-clamped; masked at store)
  short8 bfrag[4][4];
#pragma unroll
  for (int nt = 0; nt < 4; ++nt) {
    const int colc = nbase + nt * 16 + l16;
    const int col = (colc < ITEM) ? colc : (ITEM - 1);
#pragma unroll
    for (int ks = 0; ks < 4; ++ks) {
      short8 bf;
      const int kb = ks * 32 + quad * 8;
#pragma unroll
      for (int j = 0; j < 8; ++j)
        bf[j] = (short)f2b(W[(size_t)(kb + j) * ITEM + col]);
      bfrag[nt][ks] = bf;
    }
  }
  // write-phase lane mapping: this lane stores cols c4..c4+3 (ITEM%4==0 -> exact mask)
  const int c4 = nbase + l16 * 4;
  const bool wvalid = (c4 + 3) < ITEM;
  float4 bv = make_float4(0.f, 0.f, 0.f, 0.f);
  if (wvalid) bv = *(const float4*)(bias + c4);

  const int mtiles = M >> 4;
  for (int mt = blockIdx.x; mt < mtiles; mt += gridDim.x) {
    const u16* arow = A + (size_t)(mt * 16 + l16) * HC_;
    short8 af[4];
#pragma unroll
    for (int ks = 0; ks < 4; ++ks)
      af[ks] = *(const short8*)(arow + ks * 32 + quad * 8);
    f32x4 acc[4];
#pragma unroll
    for (int nt = 0; nt < 4; ++nt) acc[nt] = (f32x4){0.f, 0.f, 0.f, 0.f};
#pragma unroll
    for (int nt = 0; nt < 4; ++nt)
#pragma unroll
      for (int ks = 0; ks < 4; ++ks)
        acc[nt] = __builtin_amdgcn_mfma_f32_16x16x32_bf16(af[ks], bfrag[nt][ks],
                                                          acc[nt], 0, 0, 0);
    // fragment -> wave-private LDS tile
#pragma unroll
    for (int nt = 0; nt < 4; ++nt)
#pragma unroll
      for (int r = 0; r < 4; ++r)
        lds[wv][quad * 4 + r][nt * 16 + l16] = acc[nt][r];
    __syncthreads();
    // coalesced stores: per instr, 4 rows x 16 consecutive float4 (256B/row)
    if (wvalid) {
#pragma unroll
      for (int i = 0; i < 4; ++i) {
        const int row = (lane >> 4) + i * 4;
        float4 v = *(const float4*)(&lds[wv][row][l16 * 4]);
        v.x += bv.x; v.y += bv.y; v.z += bv.z; v.w += bv.w;
        *(float4*)(out + (size_t)(mt * 16 + row) * ITEM + c4) = v;
      }
    }
    __syncthreads();
  }
}

// =======================================================================
extern "C" void kernel_launch(void* const* d_in, const int* in_sizes, int n_in,
                              void* d_out, int out_size, void* d_ws, size_t ws_size,
                              hipStream_t stream)
{
  (void)n_in; (void)out_size; (void)ws_size;
  const int* node_idx = (const int*)d_in[0];
  const int* eidx     = (const int*)d_in[1];
  const int* etype    = (const int*)d_in[2];
  const int* toff0    = (const int*)d_in[3];
  const int* toff1    = (const int*)d_in[4];
  const int* dist0    = (const int*)d_in[5];
  const int* dist1    = (const int*)d_in[6];
  const int* center   = (const int*)d_in[7];
  const float* id_emb   = (const float*)d_in[8];
  const float* u_att    = (const float*)d_in[9];
  const float* i_att    = (const float*)d_in[10];
  const float* t_att    = (const float*)d_in[11];
  const float* u_emb    = (const float*)d_in[12];
  const float* i_emb    = (const float*)d_in[13];
  const float* t_emb    = (const float*)d_in[14];
  const float* u_att2   = (const float*)d_in[15];
  const float* i_att2   = (const float*)d_in[16];
  const float* t_att2   = (const float*)d_in[17];
  const float* u_emb2   = (const float*)d_in[18];
  const float* i_emb2   = (const float*)d_in[19];
  const float* t_emb2   = (const float*)d_in[20];
  const float* ud_att   = (const float*)d_in[21];
  const float* id_att   = (const float*)d_in[22];
  const float* ud_emb   = (const float*)d_in[23];
  const float* id_embd  = (const float*)d_in[24];
  const float* ud_att2  = (const float*)d_in[25];
  const float* id_att2  = (const float*)d_in[26];
  const float* ud_emb2  = (const float*)d_in[27];
  const float* id_emb2  = (const float*)d_in[28];
  const float* trans_head = (const float*)d_in[29];
  const float* rnn_w    = (const float*)d_in[30];
  const float* w1       = (const float*)d_in[31];
  const float* b1       = (const float*)d_in[32];
  const float* w2       = (const float*)d_in[33];
  const float* b2       = (const float*)d_in[34];
  const float* wl0      = (const float*)d_in[35];
  const float* wr0      = (const float*)d_in[36];
  const float* asrc0    = (const float*)d_in[37];
  const float* adst0    = (const float*)d_in[38];
  const float* wl1      = (const float*)d_in[39];
  const float* wr1      = (const float*)d_in[40];
  const float* asrc1    = (const float*)d_in[41];
  const float* adst1    = (const float*)d_in[42];

  const int N_    = in_sizes[0];
  const int E_    = in_sizes[2];
  const int B_    = in_sizes[7];
  const int ITEM_ = in_sizes[34];
  const int* esrc = eidx;
  const int* edst = eidx + E_;

  // ---- workspace carve-up (256B aligned), ~155 MB ----
  char* ws = (char*)d_ws;
  size_t off = 0;
  auto alloc = [&](size_t bytes) -> char* {
    char* p = ws + off;
    off += (bytes + 255) & ~(size_t)255;
    return p;
  };
  float* CO_b  = (float*)alloc((size_t)N_ * HC_ * 4);   // 25.6M
  u16*   k_b   = (u16*)  alloc((size_t)N_ * HC_ * 2);   // 12.8M
  u16*   x_b   = (u16*)  alloc((size_t)N_ * HC_ * 2);   // 12.8M
  u16*   h1_b  = (u16*)  alloc((size_t)N_ * HC_ * 2);   // 12.8M
  float* kdot0 = (float*)alloc((size_t)N_ * 4 * 4);
  float* kdot1 = (float*)alloc((size_t)N_ * 4 * 4);
  float* qdot  = (float*)alloc((size_t)N_ * 4 * 4);
  float* dots  = (float*)alloc((size_t)DOT_ROWS * 4 * 4);
  float* wq    = (float*)alloc(1024 * 4);               // wq0 | wq1
  u16*   rnn_wb= (u16*)  alloc(256 * HC_ * 2);          // bf16 copy of rnn_w
  u16*   Wt    = (u16*)  alloc(HC_ * HC_ * 2);          // bf16(trans_head @ rnn_w_bot)
  u16*   hdd   = (u16*)  alloc((size_t)B_ * HC_ * 2);
  int*   cur   = (int*)  alloc((size_t)N_ * 4);         // bucket counts
  int2*  m0a   = (int2*) alloc((size_t)N_ * CAP * 8);   // 12.8M
  int2*  m1a   = (int2*) alloc((size_t)N_ * CAP * 8);   // 12.8M
  f32x4* e0a   = (f32x4*)alloc((size_t)N_ * CAP * 16);  // 25.6M
  f32x4* e1a   = (f32x4*)alloc((size_t)N_ * CAP * 16);  // 25.6M

  const int TB = 256;
  auto nb = [&](long long t) { return (int)((t + TB - 1) / TB); };

  // 1) fused prolog (zero cur/kdot0/kdot1, gather x, dots, wq, cvt rnn, Wt)
  const int nbCur  = (N_ + 255) / 256;
  const int nbKd   = (N_ * 4 + 255) / 256;
  const int nbGx   = (N_ * 16 + 255) / 256;
  const int nbDots = (DOT_ROWS * 4 + 255) / 256;
  const int prologBlocks = nbCur + nbKd + nbGx + nbDots + 4 + 128 + 64;
  prolog_k<<<prologBlocks, TB, 0, stream>>>(
      node_idx, id_emb, x_b,
      u_att, i_att, t_att, ud_att, id_att,
      u_att2, i_att2, t_att2, ud_att2, id_att2,
      asrc0, asrc1, dots,
      wr0, adst0, wr1, adst1, wq,
      rnn_w, rnn_wb, trans_head, Wt,
      cur, kdot0, kdot1, N_);

  // 2) bucket fill (SoA; pre-sums edge att-dots for both layers)
  fill_k<<<nb(E_), TB, 0, stream>>>(esrc, edst, etype, toff0, toff1, dist0, dist1,
                                    dots, cur, m0a, e0a, m1a, e1a, E_);

  // 3) layer 0: k0 = x @ wl0 with fused kdot0/qdot epilogue
  gemm_k<0,0,4,0,0,1><<<dim3(640, 2), TB, 0, stream>>>(
      x_b, wl0, nullptr, k_b, asrc0, wq, kdot0, qdot, N_, HC_);

  // 4) layer-0 fused attention+aggregate
  conv_k<0><<<nb((long long)N_ * 64), TB, 0, stream>>>(
      cur, m0a, e0a, k_b, kdot0, qdot,
      u_emb, i_emb, t_emb, ud_emb, id_embd, nullptr, CO_b, N_);

  // 5) h1 = tanh(CO @ rnn_w_top + x @ Wt)
  gemm2_k<<<dim3(640, 2), TB, 0, stream>>>(CO_b, rnn_wb, x_b, Wt, h1_b, N_);

  // 6) layer 1: k1 = relu(h1) @ wl1 with fused kdot1/qdot epilogue
  gemm_k<0,1,4,0,0,1><<<dim3(640, 2), TB, 0, stream>>>(
      h1_b, wl1, nullptr, k_b, asrc1, wq + 512, kdot1, qdot, N_, HC_);

  // 7) layer-1 fused attention+aggregate, center nodes only
  conv_k<1><<<nb((long long)B_ * 64), TB, 0, stream>>>(
      cur, m1a, e1a, k_b, kdot1, qdot,
      u_emb2, i_emb2, t_emb2, ud_emb2, id_emb2, center, CO_b, B_);

  // 8) merged: h2 (LDS) + hdd = lrelu([x|h1|h2][center] @ w1 + b1)
  gh_k<<<B_ / 16, TB, 0, stream>>>(CO_b, rnn_wb, h1_b, x_b, center, w1, b1, hdd);

  // 9) logits = hdd @ w2 + b2 -> d_out (fp32), coalesced 256B-segment stores
  gemm_out_k<<<dim3(8, (ITEM_ + 255) / 256), TB, 0, stream>>>(
      hdd, w2, b2, (float*)d_out, B_, ITEM_);
}

// Round 6
// 559.477 us; speedup vs baseline: 1.2148x; 1.1346x over previous
//
#include <hip/hip_runtime.h>
#include <cstdint>
#include <cstddef>

typedef unsigned short u16;
typedef __attribute__((ext_vector_type(8))) short short8;
typedef __attribute__((ext_vector_type(4))) float f32x4;

// ---------- constants (match reference) ----------
#define HC_ 128
#define CAP 32            // in-degree bucket capacity (Poisson(4) tail ~1e-18)
// dot-table row offsets (rows of 4 floats)
#define OFF_U0   0
#define OFF_I0   202
#define OFF_T0   404
#define OFF_UD0  606
#define OFF_ID0  1107
#define OFF_U2   1608
#define OFF_I2   2410
#define OFF_T2   3212
#define OFF_UD2  4014
#define OFF_ID2  4515
#define DOT_ROWS 5016

__device__ __forceinline__ float b2f(u16 u) {
  union { unsigned int i; float f; } v; v.i = ((unsigned int)u) << 16; return v.f;
}
__device__ __forceinline__ u16 f2b(float f) {
  union { float f; unsigned int i; } v; v.f = f;
  unsigned int r = v.i + 0x7fffu + ((v.i >> 16) & 1u);
  return (u16)(r >> 16);
}

// ================= fused prolog ========================================================
// zero cur/kdot (incl. sentinel rows), set center masks, gather x (+zero sentinel),
// dots, wq, cvt rnn, Wt.  (mask0/mask1/mask2/cnts are zeroed by hipMemsetAsync BEFORE
// this kernel so the center-set segment cannot race a zeroing segment.)
__global__ __launch_bounds__(256) void prolog_k(
    const int* __restrict__ nidx, const float* __restrict__ emb, u16* __restrict__ x,
    const float* u0, const float* i0, const float* t0, const float* ud0, const float* id0,
    const float* u2, const float* i2, const float* t2, const float* ud2, const float* id2,
    const float* __restrict__ asrc0, const float* __restrict__ asrc1,
    float* __restrict__ dots,
    const float* __restrict__ wr0, const float* __restrict__ adst0,
    const float* __restrict__ wr1, const float* __restrict__ adst1,
    float* __restrict__ wq,
    const float* __restrict__ rnn_w, u16* __restrict__ rnn_wb,
    const float* __restrict__ th, u16* __restrict__ Wt,
    int* __restrict__ cur, float* __restrict__ kdot0, float* __restrict__ kdot1,
    int* __restrict__ mask1, int* __restrict__ mask2,
    const int* __restrict__ center, int B_, int Nn)
{
  int b = blockIdx.x, t = threadIdx.x;
  const int nbZ    = (Nn + 16 + 255) >> 8;
  const int nbC    = (B_ + 255) >> 8;
  const int nbGx   = ((Nn + 16) * 16 + 255) >> 8;
  const int nbDots = (DOT_ROWS * 4 + 255) >> 8;

  if (b < nbZ) {   // zero cur + kdot (N+16 rows each)
    int i = b * 256 + t;
    if (i < Nn + 16) {
      cur[i] = 0;
      f32x4 z = {0.f, 0.f, 0.f, 0.f};
      *(f32x4*)(kdot0 + (size_t)i * 4) = z;
      *(f32x4*)(kdot1 + (size_t)i * 4) = z;
    }
    return;
  }
  b -= nbZ;
  if (b < nbC) {   // mark centers (mask arrays pre-zeroed by memset)
    int i = b * 256 + t;
    if (i < B_) { int c = center[i]; mask2[c] = 1; mask1[c] = 1; }
    return;
  }
  b -= nbC;
  if (b < nbGx) {  // x = bf16(id_emb[node_idx]); sentinel rows [N, N+16) = 0
    int i = b * 256 + t;
    int n = i >> 4, c = (i & 15) << 3;
    if (n < Nn) {
      int id = nidx[n];
      const float* s = emb + (size_t)id * HC_ + c;
      u16 tmp[8];
#pragma unroll
      for (int j = 0; j < 8; ++j) tmp[j] = f2b(s[j]);
      *(short8*)(x + (size_t)n * HC_ + c) = *(short8*)tmp;
    } else if (n < Nn + 16) {
      short8 z = {0,0,0,0,0,0,0,0};
      *(short8*)(x + (size_t)n * HC_ + c) = z;
    }
    return;
  }
  b -= nbGx;
  if (b < nbDots) {  // att-bias dot tables
    int i = b * 256 + t;
    if (i < DOT_ROWS * 4) {
      int r = i >> 2, h = i & 3;
      const float* tab; int lr; const float* as;
      if      (r < OFF_I0)  { tab = u0;  lr = r;            as = asrc0; }
      else if (r < OFF_T0)  { tab = i0;  lr = r - OFF_I0;   as = asrc0; }
      else if (r < OFF_UD0) { tab = t0;  lr = r - OFF_T0;   as = asrc0; }
      else if (r < OFF_ID0) { tab = ud0; lr = r - OFF_UD0;  as = asrc0; }
      else if (r < OFF_U2)  { tab = id0; lr = r - OFF_ID0;  as = asrc0; }
      else if (r < OFF_I2)  { tab = u2;  lr = r - OFF_U2;   as = asrc1; }
      else if (r < OFF_T2)  { tab = i2;  lr = r - OFF_I2;   as = asrc1; }
      else if (r < OFF_UD2) { tab = t2;  lr = r - OFF_T2;   as = asrc1; }
      else if (r < OFF_ID2) { tab = ud2; lr = r - OFF_UD2;  as = asrc1; }
      else                  { tab = id2; lr = r - OFF_ID2;  as = asrc1; }
      float s = 0.f;
#pragma unroll
      for (int c = 0; c < 32; ++c)
        s += tab[(size_t)lr * HC_ + h * 32 + c] * as[h * 32 + c];
      dots[i] = s;
    }
    return;
  }
  b -= nbDots;
  if (b < 4) {  // wq[layer][k][h]
    int i = b * 256 + t;
    int layer = i >> 9, k = (i >> 2) & 127, h = i & 3;
    const float* wr = layer ? wr1 : wr0;
    const float* ad = layer ? adst1 : adst0;
    float s = 0.f;
#pragma unroll
    for (int c = 0; c < 32; ++c)
      s += wr[(size_t)k * HC_ + h * 32 + c] * ad[h * 32 + c];
    wq[i] = s;
    return;
  }
  b -= 4;
  if (b < 128) {  // rnn_w -> bf16
    int i = b * 256 + t;
    rnn_wb[i] = f2b(rnn_w[i]);
    return;
  }
  b -= 128;
  {  // Wt = bf16(trans_head @ rnn_w[128:,:]), 16384 outputs
    int i = b * 256 + t;
    if (i < 16384) {
      int r = i >> 7, c = i & 127;
      float s = 0.f;
#pragma unroll 8
      for (int k = 0; k < 128; ++k)
        s += th[r * 128 + k] * rnn_w[(size_t)(128 + k) * 128 + c];
      Wt[i] = f2b(s);
    }
  }
}

// ================= bucket fill (SoA) + mark U1 srcs ====================================
__global__ void fill_k(const int* __restrict__ src, const int* __restrict__ dst,
                       const int* __restrict__ ety,
                       const int* __restrict__ toff0, const int* __restrict__ toff1,
                       const int* __restrict__ dist0, const int* __restrict__ dist1,
                       const float* __restrict__ dots,
                       int* __restrict__ cur,
                       int2* __restrict__ m0a, f32x4* __restrict__ e0a,
                       int2* __restrict__ m1a, f32x4* __restrict__ e1a,
                       const int* __restrict__ mask2, int* __restrict__ mask1, int E)
{
  int e = blockIdx.x * blockDim.x + threadIdx.x;
  if (e >= E) return;
  int d = dst[e];
  int s = src[e];
  if (mask2[d]) mask1[s] = 1;          // srcs feeding a center dst need h1
  int slot = atomicAdd(&cur[d], 1);
  if (slot >= CAP) return;   // statistically unreachable
  int ty = ety[e];
  int to0 = toff0[e], to1 = toff1[e], di0 = dist0[e], di1 = dist1[e];
  bool inv = (ty == 0 || ty == 2 || ty == 3);
  int ar0 = (ty == 0) ? (OFF_U0 + to0) : (ty < 2) ? (OFF_I0 + to0) : (OFF_T0 + to0);
  int ar1 = (ty == 0) ? (OFF_U2 + to1) : (ty < 2) ? (OFF_I2 + to1) : (OFF_T2 + to1);
  f32x4 e0 = *(const f32x4*)(dots + (size_t)ar0 * 4);
  f32x4 e1 = *(const f32x4*)(dots + (size_t)ar1 * 4);
  if (inv) {
    int dr0 = ((ty == 0) ? OFF_UD0 : OFF_ID0) + di0;
    int dr1 = ((ty == 0) ? OFF_UD2 : OFF_ID2) + di1;
    e0 += *(const f32x4*)(dots + (size_t)dr0 * 4);
    e1 += *(const f32x4*)(dots + (size_t)dr1 * 4);
  }
  size_t ix = (size_t)d * CAP + slot;
  m0a[ix] = make_int2(s, ty | (to0 << 3) | (di0 << 13));
  m1a[ix] = make_int2(s, ty | (to1 << 3) | (di1 << 13));
  e0a[ix] = e0;
  e1a[ix] = e1;
}

// ================= mark U0 = srcs of edges into U1 =====================================
__global__ void mark0_k(const int* __restrict__ esrc, const int* __restrict__ edst,
                        const int* __restrict__ mask1, int* __restrict__ mask0, int E)
{
  int e = blockIdx.x * blockDim.x + threadIdx.x;
  if (e < E && mask1[edst[e]]) mask0[esrc[e]] = 1;
}

// ================= compact masks -> lists (unordered) ==================================
__global__ void compact_k(const int* __restrict__ mask0, const int* __restrict__ mask1,
                          int* __restrict__ L0, int* __restrict__ L1,
                          int* __restrict__ cnts, int Nn)
{
  int n = blockIdx.x * blockDim.x + threadIdx.x;
  if (n >= Nn) return;
  int m1 = mask1[n];
  if (m1 | mask0[n]) L0[atomicAdd(&cnts[0], 1)] = n;
  if (m1)            L1[atomicAdd(&cnts[1], 1)] = n;
}

// ---------- gather k-GEMM with fused kdot/qdot epilogue: C[g] = [relu]A[g] @ W ---------
// rows from list[0..cnt); tile padding uses sentinel row Nsent (kdot/qdot there unread)
template<int RELUA>
__global__ __launch_bounds__(256) void gemm_kq_g(
    const u16* __restrict__ A, const float* __restrict__ W, u16* __restrict__ C,
    const float* __restrict__ asrc, const float* __restrict__ wqt,
    float* __restrict__ kdot, float* __restrict__ qdot,
    const int* __restrict__ list, const int* __restrict__ cnts, int ci, int Nsent)
{
  const int lane = threadIdx.x & 63;
  const int wave = threadIdx.x >> 6;
  const int quad = lane >> 4;
  const int l16  = lane & 15;
  const int by   = blockIdx.y;
  const int n0   = by * 64 + wave * 16;

  short8 bfrag[4];
#pragma unroll
  for (int ks = 0; ks < 4; ++ks) {
    short8 bf;
    const int kb = ks * 32 + quad * 8;
#pragma unroll
    for (int j = 0; j < 8; ++j)
      bf[j] = (short)f2b(W[(size_t)(kb + j) * HC_ + n0 + l16]);
    bfrag[ks] = bf;
  }
  const int hh = n0 >> 5;
  const float asv = asrc[n0 + l16];

  const int cnt = cnts[ci];
  const int mtiles = (cnt + 15) >> 4;
  for (int mt = blockIdx.x; mt < mtiles; mt += gridDim.x) {
    const int rA = mt * 16 + l16;
    const int gA = (rA < cnt) ? list[rA] : Nsent;
    const u16* arow = A + (size_t)gA * HC_;
    f32x4 acc = {0.f, 0.f, 0.f, 0.f};
    float qp[4] = {0.f, 0.f, 0.f, 0.f};
#pragma unroll
    for (int ks = 0; ks < 4; ++ks) {
      short8 af = *(const short8*)(arow + ks * 32 + quad * 8);
      if (RELUA) {
#pragma unroll
        for (int j = 0; j < 8; ++j) af[j] = (af[j] < (short)0) ? (short)0 : af[j];
      }
#pragma unroll
      for (int j = 0; j < 8; ++j) {
        float v = b2f((u16)af[j]);
        const float* wr = wqt + (size_t)(ks * 32 + quad * 8 + j) * 4;
        qp[0] += v * wr[0]; qp[1] += v * wr[1];
        qp[2] += v * wr[2]; qp[3] += v * wr[3];
      }
      acc = __builtin_amdgcn_mfma_f32_16x16x32_bf16(af, bfrag[ks], acc, 0, 0, 0);
    }
    // qdot[gA] = full-K sum (reduce partials across quads)
#pragma unroll
    for (int h = 0; h < 4; ++h) {
      qp[h] += __shfl_xor(qp[h], 16, 64);
      qp[h] += __shfl_xor(qp[h], 32, 64);
    }
    if (by == 0 && quad == 0) {
      f32x4 qv; qv[0] = qp[0]; qv[1] = qp[1]; qv[2] = qp[2]; qv[3] = qp[3];
      *(f32x4*)(qdot + (size_t)gA * 4) = qv;
    }
    // output rows of this lane's fragment
    int gC[4];
#pragma unroll
    for (int r = 0; r < 4; ++r) {
      const int rC = mt * 16 + quad * 4 + r;
      gC[r] = (rC < cnt) ? list[rC] : Nsent;
    }
#pragma unroll
    for (int r = 0; r < 4; ++r) {
      float sr = acc[r] * asv;
      sr += __shfl_xor(sr, 1, 64); sr += __shfl_xor(sr, 2, 64);
      sr += __shfl_xor(sr, 4, 64); sr += __shfl_xor(sr, 8, 64);
      if (l16 == 0)
        atomicAdd(&kdot[(size_t)gC[r] * 4 + hh], sr);
    }
#pragma unroll
    for (int r = 0; r < 4; ++r)
      C[(size_t)gC[r] * HC_ + n0 + l16] = f2b(acc[r]);
  }
}

// ---------- gather rnn GEMM: h1[g] = tanh( cvt(CO[g] f32)@W1 + x[g]@W2 ), N=128 --------
__global__ __launch_bounds__(256) void gemm2_g(
    const float* __restrict__ A1, const u16* __restrict__ W1,
    const u16* __restrict__ A2, const u16* __restrict__ W2,
    u16* __restrict__ Cout,
    const int* __restrict__ list, const int* __restrict__ cnts, int ci, int Nsent)
{
  const int lane = threadIdx.x & 63;
  const int wave = threadIdx.x >> 6;
  const int quad = lane >> 4;
  const int l16  = lane & 15;
  const int n0   = blockIdx.y * 64 + wave * 16;   // N fixed 128, grid.y==2

  short8 bf1[4], bf2[4];
#pragma unroll
  for (int ks = 0; ks < 4; ++ks) {
    short8 a, b;
    const int kb = ks * 32 + quad * 8;
#pragma unroll
    for (int j = 0; j < 8; ++j) {
      a[j] = (short)W1[(size_t)(kb + j) * HC_ + n0 + l16];
      b[j] = (short)W2[(size_t)(kb + j) * HC_ + n0 + l16];
    }
    bf1[ks] = a; bf2[ks] = b;
  }

  const int cnt = cnts[ci];
  const int mtiles = (cnt + 15) >> 4;
  for (int mt = blockIdx.x; mt < mtiles; mt += gridDim.x) {
    const int rA = mt * 16 + l16;
    const int gA = (rA < cnt) ? list[rA] : Nsent;
    const float* a1 = A1 + (size_t)gA * HC_;
    const u16*   a2 = A2 + (size_t)gA * HC_;
    f32x4 acc = {0.f, 0.f, 0.f, 0.f};
#pragma unroll
    for (int ks = 0; ks < 4; ++ks) {
      short8 af;
      const float* p = a1 + ks * 32 + quad * 8;
#pragma unroll
      for (int j = 0; j < 8; ++j) af[j] = (short)f2b(p[j]);
      acc = __builtin_amdgcn_mfma_f32_16x16x32_bf16(af, bf1[ks], acc, 0, 0, 0);
    }
#pragma unroll
    for (int ks = 0; ks < 4; ++ks) {
      short8 af = *(const short8*)(a2 + ks * 32 + quad * 8);
      acc = __builtin_amdgcn_mfma_f32_16x16x32_bf16(af, bf2[ks], acc, 0, 0, 0);
    }
#pragma unroll
    for (int r = 0; r < 4; ++r) {
      const int rC = mt * 16 + quad * 4 + r;
      const int gC = (rC < cnt) ? list[rC] : Nsent;
      Cout[(size_t)gC * HC_ + n0 + l16] = f2b(tanhf(acc[r]));
    }
  }
}

// ========= fused conv: per-dst gather over fixed-cap buckets; LDS alpha cache ==========
// One wave per destination node drawn from list[0..bound); grid-stride over waves.
template<int DEVCNT>
__global__ __launch_bounds__(256) void conv_k(
    const int* __restrict__ cur, const int2* __restrict__ meta,
    const f32x4* __restrict__ edot,
    const u16* __restrict__ kbuf,
    const float* __restrict__ kdot, const float* __restrict__ qdot,
    const float* __restrict__ uemb, const float* __restrict__ iemb,
    const float* __restrict__ temb,
    const float* __restrict__ udemb, const float* __restrict__ idemb,
    const int* __restrict__ list, const int* __restrict__ cnts, int ci, int cntConst,
    float* __restrict__ CO)
{
  __shared__ float als[4][CAP][4];
  const int wv = threadIdx.x >> 6;
  const int lane = threadIdx.x & 63;
  const int bound = DEVCNT ? cnts[ci] : cntConst;
  const int wstep = gridDim.x * 4;
  const int h0 = lane >> 5;       // head of channel lane     (0 or 1)
  const int h1 = h0 + 2;          // head of channel lane+64  (2 or 3)

  for (int wid = (blockIdx.x * blockDim.x + threadIdx.x) >> 6; wid < bound; wid += wstep) {
    const int n = list[wid];
    int cnt = cur[n]; if (cnt > CAP) cnt = CAP;
    const float q0 = qdot[n * 4 + h0];
    const float q1 = qdot[n * 4 + h1];
    const int2* mb = meta + (size_t)n * CAP;
    const f32x4* eb = edot + (size_t)n * CAP;

    float den0 = 0.f, den1 = 0.f;
    for (int e = 0; e < cnt; ++e) {
      int s = mb[e].x;
      f32x4 ed = eb[e];
      float l0 = kdot[s * 4 + h0] + q0 + ed[h0];
      float l1 = kdot[s * 4 + h1] + q1 + ed[h1];
      l0 = (l0 > 0.f) ? l0 : 0.2f * l0;
      l1 = (l1 > 0.f) ? l1 : 0.2f * l1;
      float a0 = __expf(fminf(l0, 30.f));
      float a1 = __expf(fminf(l1, 30.f));
      den0 += a0; den1 += a1;
      if ((lane & 31) == 0) { als[wv][e][h0] = a0; als[wv][e][h1] = a1; }
    }
    const float r0 = 1.f / fmaxf(den0, 1e-16f);
    const float r1 = 1.f / fmaxf(den1, 1e-16f);

    float acc0 = 0.f, acc1 = 0.f;
    for (int e = 0; e < cnt; ++e) {
      int2 mrec = mb[e];
      int s = mrec.x;
      int ty = mrec.y & 7, to = (mrec.y >> 3) & 1023, di = mrec.y >> 13;
      float al0 = als[wv][e][h0] * r0;
      float al1 = als[wv][e][h1] * r1;

      float m0 = b2f(kbuf[(size_t)s * HC_ + lane]);
      float m1 = b2f(kbuf[(size_t)s * HC_ + 64 + lane]);
      const float* et = (ty == 0) ? uemb : (ty < 2) ? iemb : temb;
      m0 += et[(size_t)to * HC_ + lane];
      m1 += et[(size_t)to * HC_ + 64 + lane];
      if (ty == 0 || ty == 2 || ty == 3) {
        const float* dt = (ty == 0) ? udemb : idemb;
        m0 += dt[(size_t)di * HC_ + lane];
        m1 += dt[(size_t)di * HC_ + 64 + lane];
      }
      acc0 += al0 * m0;
      acc1 += al1 * m1;
    }
    CO[(size_t)n * HC_ + lane]      = acc0;
    CO[(size_t)n * HC_ + 64 + lane] = acc1;
  }
}

// ========= merged h2 + pred-head layer 1 (one block per 16-row m-tile of B) ===========
__global__ __launch_bounds__(256) void gh_k(
    const float* __restrict__ CO, const u16* __restrict__ rnn_wb,
    const u16* __restrict__ h1, const u16* __restrict__ xb,
    const int* __restrict__ center, const float* __restrict__ w1,
    const float* __restrict__ b1, u16* __restrict__ hdd)
{
  __shared__ u16 h2s[16][136];   // +8 pad: 272B row stride (16B-aligned, low conflict)
  const int t = threadIdx.x;
  const int lane = t & 63, wave = t >> 6, quad = lane >> 4, l16 = lane & 15;
  const int mt = blockIdx.x;
  const int rowm = mt * 16 + l16;
  const int nid = center[rowm];
  const u16* W1 = rnn_wb;                 // rnn top half (rows 0..127)
  const u16* W2 = rnn_wb + HC_ * HC_;     // rnn bottom half

  // ---- phase G ----
#pragma unroll
  for (int half = 0; half < 2; ++half) {
    const int n0 = half * 64 + wave * 16;
    short8 bf1[4], bf2[4];
#pragma unroll
    for (int ks = 0; ks < 4; ++ks) {
      short8 a, b;
      const int kb = ks * 32 + quad * 8;
#pragma unroll
      for (int j = 0; j < 8; ++j) {
        a[j] = (short)W1[(size_t)(kb + j) * HC_ + n0 + l16];
        b[j] = (short)W2[(size_t)(kb + j) * HC_ + n0 + l16];
      }
      bf1[ks] = a; bf2[ks] = b;
    }
    const float* a1 = CO + (size_t)nid * HC_;
    const u16*   a2 = h1 + (size_t)nid * HC_;
    f32x4 acc = {0.f, 0.f, 0.f, 0.f};
#pragma unroll
    for (int ks = 0; ks < 4; ++ks) {
      short8 af;
      const float* p = a1 + ks * 32 + quad * 8;
#pragma unroll
      for (int j = 0; j < 8; ++j) af[j] = (short)f2b(p[j]);
      acc = __builtin_amdgcn_mfma_f32_16x16x32_bf16(af, bf1[ks], acc, 0, 0, 0);
    }
#pragma unroll
    for (int ks = 0; ks < 4; ++ks) {
      short8 af = *(const short8*)(a2 + ks * 32 + quad * 8);
#pragma unroll
      for (int j = 0; j < 8; ++j) af[j] = (af[j] < (short)0) ? (short)0 : af[j];
      acc = __builtin_amdgcn_mfma_f32_16x16x32_bf16(af, bf2[ks], acc, 0, 0, 0);
    }
#pragma unroll
    for (int r = 0; r < 4; ++r)
      h2s[quad * 4 + r][n0 + l16] = f2b(tanhf(acc[r]));
  }
  __syncthreads();

  // ---- phase H ----
#pragma unroll
  for (int half = 0; half < 2; ++half) {
    const int n0 = half * 64 + wave * 16;
    short8 bfrag[12];
#pragma unroll
    for (int ks = 0; ks < 12; ++ks) {
      short8 bf;
      const int kb = ks * 32 + quad * 8;
#pragma unroll
      for (int j = 0; j < 8; ++j)
        bf[j] = (short)f2b(w1[(size_t)(kb + j) * HC_ + n0 + l16]);
      bfrag[ks] = bf;
    }
    const float bv = b1[n0 + l16];
    f32x4 acc = {0.f, 0.f, 0.f, 0.f};
#pragma unroll
    for (int ks = 0; ks < 12; ++ks) {
      short8 af;
      if (ks < 4)
        af = *(const short8*)(xb + (size_t)nid * HC_ + ks * 32 + quad * 8);
      else if (ks < 8)
        af = *(const short8*)(h1 + (size_t)nid * HC_ + (ks - 4) * 32 + quad * 8);
      else
        af = *(const short8*)(&h2s[l16][(ks - 8) * 32 + quad * 8]);
      acc = __builtin_amdgcn_mfma_f32_16x16x32_bf16(af, bfrag[ks], acc, 0, 0, 0);
    }
#pragma unroll
    for (int r = 0; r < 4; ++r) {
      float v = acc[r] + bv;
      v = (v > 0.f) ? v : 0.2f * v;
      hdd[(size_t)(mt * 16 + quad * 4 + r) * HC_ + n0 + l16] = f2b(v);
    }
  }
}

// ========= final logits GEMM: out[M,ITEM] = hdd @ w2 + b2, coalesced 256B writes =======
__global__ __launch_bounds__(256) void gemm_out_k(
    const u16* __restrict__ A, const float* __restrict__ W,
    const float* __restrict__ bias, float* __restrict__ out, int M, int ITEM)
{
  __shared__ float lds[4][16][68];   // per-wave [16 rows][64 cols + 4 pad]
  const int lane = threadIdx.x & 63;
  const int wv   = threadIdx.x >> 6;
  const int quad = lane >> 4;
  const int l16  = lane & 15;
  const int nbase = blockIdx.y * 256 + wv * 64;

  short8 bfrag[4][4];
#pragma unroll
  for (int nt = 0; nt < 4; ++nt) {
    const int colc = nbase + nt * 16 + l16;
    const int col = (colc < ITEM) ? colc : (ITEM - 1);
#pragma unroll
    for (int ks = 0; ks < 4; ++ks) {
      short8 bf;
      const int kb = ks * 32 + quad * 8;
#pragma unroll
      for (int j = 0; j < 8; ++j)
        bf[j] = (short)f2b(W[(size_t)(kb + j) * ITEM + col]);
      bfrag[nt][ks] = bf;
    }
  }
  const int c4 = nbase + l16 * 4;
  const bool wvalid = (c4 + 3) < ITEM;
  float4 bv = make_float4(0.f, 0.f, 0.f, 0.f);
  if (wvalid) bv = *(const float4*)(bias + c4);

  const int mtiles = M >> 4;
  for (int mt = blockIdx.x; mt < mtiles; mt += gridDim.x) {
    const u16* arow = A + (size_t)(mt * 16 + l16) * HC_;
    short8 af[4];
#pragma unroll
    for (int ks = 0; ks < 4; ++ks)
      af[ks] = *(const short8*)(arow + ks * 32 + quad * 8);
    f32x4 acc[4];
#pragma unroll
    for (int nt = 0; nt < 4; ++nt) acc[nt] = (f32x4){0.f, 0.f, 0.f, 0.f};
#pragma unroll
    for (int nt = 0; nt < 4; ++nt)
#pragma unroll
      for (int ks = 0; ks < 4; ++ks)
        acc[nt] = __builtin_amdgcn_mfma_f32_16x16x32_bf16(af[ks], bfrag[nt][ks],
                                                          acc[nt], 0, 0, 0);
#pragma unroll
    for (int nt = 0; nt < 4; ++nt)
#pragma unroll
      for (int r = 0; r < 4; ++r)
        lds[wv][quad * 4 + r][nt * 16 + l16] = acc[nt][r];
    __syncthreads();
    if (wvalid) {
#pragma unroll
      for (int i = 0; i < 4; ++i) {
        const int row = (lane >> 4) + i * 4;
        float4 v = *(const float4*)(&lds[wv][row][l16 * 4]);
        v.x += bv.x; v.y += bv.y; v.z += bv.z; v.w += bv.w;
        *(float4*)(out + (size_t)(mt * 16 + row) * ITEM + c4) = v;
      }
    }
    __syncthreads();
  }
}

// =======================================================================
extern "C" void kernel_launch(void* const* d_in, const int* in_sizes, int n_in,
                              void* d_out, int out_size, void* d_ws, size_t ws_size,
                              hipStream_t stream)
{
  (void)n_in; (void)out_size; (void)ws_size;
  const int* node_idx = (const int*)d_in[0];
  const int* eidx     = (const int*)d_in[1];
  const int* etype    = (const int*)d_in[2];
  const int* toff0    = (const int*)d_in[3];
  const int* toff1    = (const int*)d_in[4];
  const int* dist0    = (const int*)d_in[5];
  const int* dist1    = (const int*)d_in[6];
  const int* center   = (const int*)d_in[7];
  const float* id_emb   = (const float*)d_in[8];
  const float* u_att    = (const float*)d_in[9];
  const float* i_att    = (const float*)d_in[10];
  const float* t_att    = (const float*)d_in[11];
  const float* u_emb    = (const float*)d_in[12];
  const float* i_emb    = (const float*)d_in[13];
  const float* t_emb    = (const float*)d_in[14];
  const float* u_att2   = (const float*)d_in[15];
  const float* i_att2   = (const float*)d_in[16];
  const float* t_att2   = (const float*)d_in[17];
  const float* u_emb2   = (const float*)d_in[18];
  const float* i_emb2   = (const float*)d_in[19];
  const float* t_emb2   = (const float*)d_in[20];
  const float* ud_att   = (const float*)d_in[21];
  const float* id_att   = (const float*)d_in[22];
  const float* ud_emb   = (const float*)d_in[23];
  const float* id_embd  = (const float*)d_in[24];
  const float* ud_att2  = (const float*)d_in[25];
  const float* id_att2  = (const float*)d_in[26];
  const float* ud_emb2  = (const float*)d_in[27];
  const float* id_emb2  = (const float*)d_in[28];
  const float* trans_head = (const float*)d_in[29];
  const float* rnn_w    = (const float*)d_in[30];
  const float* w1       = (const float*)d_in[31];
  const float* b1       = (const float*)d_in[32];
  const float* w2       = (const float*)d_in[33];
  const float* b2       = (const float*)d_in[34];
  const float* wl0      = (const float*)d_in[35];
  const float* wr0      = (const float*)d_in[36];
  const float* asrc0    = (const float*)d_in[37];
  const float* adst0    = (const float*)d_in[38];
  const float* wl1      = (const float*)d_in[39];
  const float* wr1      = (const float*)d_in[40];
  const float* asrc1    = (const float*)d_in[41];
  const float* adst1    = (const float*)d_in[42];

  const int N_    = in_sizes[0];
  const int E_    = in_sizes[2];
  const int B_    = in_sizes[7];
  const int ITEM_ = in_sizes[34];
  const int* esrc = eidx;
  const int* edst = eidx + E_;

  // ---- workspace carve-up (256B aligned) ----
  char* ws = (char*)d_ws;
  size_t off = 0;
  auto alloc = [&](size_t bytes) -> char* {
    char* p = ws + off;
    off += (bytes + 255) & ~(size_t)255;
    return p;
  };
  const int NS = N_ + 16;   // +16 sentinel rows for tile padding
  float* CO_b  = (float*)alloc((size_t)NS * HC_ * 4);
  u16*   k_b   = (u16*)  alloc((size_t)NS * HC_ * 2);
  u16*   x_b   = (u16*)  alloc((size_t)NS * HC_ * 2);
  u16*   h1_b  = (u16*)  alloc((size_t)NS * HC_ * 2);
  float* kdot0 = (float*)alloc((size_t)NS * 4 * 4);
  float* kdot1 = (float*)alloc((size_t)NS * 4 * 4);
  float* qdot  = (float*)alloc((size_t)NS * 4 * 4);
  float* dots  = (float*)alloc((size_t)DOT_ROWS * 4 * 4);
  float* wq    = (float*)alloc(1024 * 4);               // wq0 | wq1
  u16*   rnn_wb= (u16*)  alloc(256 * HC_ * 2);          // bf16 copy of rnn_w
  u16*   Wt    = (u16*)  alloc(HC_ * HC_ * 2);          // bf16(trans_head @ rnn_w_bot)
  u16*   hdd   = (u16*)  alloc((size_t)B_ * HC_ * 2);
  int*   cur   = (int*)  alloc((size_t)NS * 4);         // bucket counts
  int2*  m0a   = (int2*) alloc((size_t)N_ * CAP * 8);
  int2*  m1a   = (int2*) alloc((size_t)N_ * CAP * 8);
  f32x4* e0a   = (f32x4*)alloc((size_t)N_ * CAP * 16);
  f32x4* e1a   = (f32x4*)alloc((size_t)N_ * CAP * 16);
  int*   maskb = (int*)  alloc(((size_t)3 * N_ + 2) * 4);  // mask0|mask1|mask2|cnts
  int*   mask0 = maskb;
  int*   mask1 = maskb + N_;
  int*   mask2 = maskb + 2 * N_;
  int*   cnts  = maskb + 3 * N_;                           // [cnt0, cnt1]
  int*   L0    = (int*)  alloc((size_t)N_ * 4);
  int*   L1    = (int*)  alloc((size_t)N_ * 4);

  const int TB = 256;
  auto nb = [&](long long t) { return (int)((t + TB - 1) / TB); };

  // 0) zero masks + counters (single memset; avoids intra-kernel zero/set race)
  hipMemsetAsync(maskb, 0, ((size_t)3 * N_ + 2) * 4, stream);

  // 1) fused prolog
  const int nbZ    = (N_ + 16 + 255) / 256;
  const int nbC    = (B_ + 255) / 256;
  const int nbGx   = ((N_ + 16) * 16 + 255) / 256;
  const int nbDots = (DOT_ROWS * 4 + 255) / 256;
  const int prologBlocks = nbZ + nbC + nbGx + nbDots + 4 + 128 + 64;
  prolog_k<<<prologBlocks, TB, 0, stream>>>(
      node_idx, id_emb, x_b,
      u_att, i_att, t_att, ud_att, id_att,
      u_att2, i_att2, t_att2, ud_att2, id_att2,
      asrc0, asrc1, dots,
      wr0, adst0, wr1, adst1, wq,
      rnn_w, rnn_wb, trans_head, Wt,
      cur, kdot0, kdot1,
      mask1, mask2, center, B_, N_);

  // 2) bucket fill (SoA) + mark U1 (srcs of center in-edges)
  fill_k<<<nb(E_), TB, 0, stream>>>(esrc, edst, etype, toff0, toff1, dist0, dist1,
                                    dots, cur, m0a, e0a, m1a, e1a, mask2, mask1, E_);

  // 3) mark U0 = srcs of edges into U1 ; 4) compact lists
  mark0_k<<<nb(E_), TB, 0, stream>>>(esrc, edst, mask1, mask0, E_);
  compact_k<<<nb(N_), TB, 0, stream>>>(mask0, mask1, L0, L1, cnts, N_);

  // 5) layer 0: k0 = x @ wl0 over L0 (U0) with fused kdot0/qdot epilogue
  gemm_kq_g<0><<<dim3(640, 2), TB, 0, stream>>>(
      x_b, wl0, k_b, asrc0, wq, kdot0, qdot, L0, cnts, 0, N_);

  // 6) layer-0 fused attention+aggregate over L1 (U1 dsts only)
  conv_k<1><<<1536, TB, 0, stream>>>(
      cur, m0a, e0a, k_b, kdot0, qdot,
      u_emb, i_emb, t_emb, ud_emb, id_embd, L1, cnts, 1, 0, CO_b);

  // 7) h1 = tanh(CO @ rnn_w_top + x @ Wt) over L1
  gemm2_g<<<dim3(640, 2), TB, 0, stream>>>(CO_b, rnn_wb, x_b, Wt, h1_b,
                                           L1, cnts, 1, N_);

  // 8) layer 1: k1 = relu(h1) @ wl1 over L1 with fused kdot1/qdot epilogue
  gemm_kq_g<1><<<dim3(640, 2), TB, 0, stream>>>(
      h1_b, wl1, k_b, asrc1, wq + 512, kdot1, qdot, L1, cnts, 1, N_);

  // 9) layer-1 fused attention+aggregate, center nodes only
  conv_k<0><<<nb((long long)B_ * 64), TB, 0, stream>>>(
      cur, m1a, e1a, k_b, kdot1, qdot,
      u_emb2, i_emb2, t_emb2, ud_emb2, id_emb2, center, nullptr, 0, B_, CO_b);

  // 10) merged: h2 (LDS) + hdd = lrelu([x|h1|h2][center] @ w1 + b1)
  gh_k<<<B_ / 16, TB, 0, stream>>>(CO_b, rnn_wb, h1_b, x_b, center, w1, b1, hdd);

  // 11) logits = hdd @ w2 + b2 -> d_out (fp32), coalesced 256B-segment stores
  gemm_out_k<<<dim3(8, (ITEM_ + 255) / 256), TB, 0, stream>>>(
      hdd, w2, b2, (float*)d_out, B_, ITEM_);
}